// Round 9
// baseline (397.561 us; speedup 1.0000x reference)
//
#include <hip/hip_runtime.h>
#include <hip/hip_bf16.h>
#include <math.h>

#define KD 128
#define NS 4096
#define NE 4096
#define NK 128
#define NNODE (NS + NE + NK)      // 8320
#define ESE 131072
#define EEK 16384
#define NCSR (2*ESE + 2*EEK)      // 294912
#define BQ 8192
#define RP (NNODE + 1)
#define HB 32                     // CSR-build blocks per graph

typedef __attribute__((ext_vector_type(8))) short short8;   // 8 bf16 (4 VGPRs)
typedef __attribute__((ext_vector_type(4))) float float4_;  // 4 fp32 acc

__device__ __forceinline__ float lrelu_(float x){ return x >= 0.f ? x : 0.2f*x; }
__device__ __forceinline__ float elu_(float x){ return x > 0.f ? x : __expf(x) - 1.f; }
__device__ __forceinline__ float sigm_(float x){ return 1.f/(1.f + __expf(-x)); }
__device__ __forceinline__ float bf2f_(unsigned short u){
  union { unsigned int i; float f; } v; v.i = ((unsigned int)u) << 16; return v.f;
}
__device__ __forceinline__ unsigned short f2b_(float x){
  __hip_bfloat16 b = __float2bfloat16(x); return *(unsigned short*)&b;
}

struct EdgePtrs { const int* s_src[3]; const int* s_dst[3]; const int* e_src[3]; const int* e_dst[3]; };

// ---------- CSR build: LDS histogram -> per-block partial counts (no global atomics) ----------
__global__ __launch_bounds__(256)
void k_hist(EdgePtrs ep, int* __restrict__ part) {
  __shared__ int hcnt[NNODE];     // 33 KB
  int g = blockIdx.y, b = blockIdx.x, t = threadIdx.x;
  for (int i = t; i < NNODE; i += 256) hcnt[i] = 0;
  __syncthreads();
  const int* ss_ = ep.s_src[g]; const int* sd_ = ep.s_dst[g];
  const int* es_ = ep.e_src[g]; const int* ed_ = ep.e_dst[g];
  int se0 = b*(ESE/HB);
  for (int i = se0 + t; i < se0 + ESE/HB; i += 256) {
    atomicAdd(&hcnt[ss_[i]], 1);
    atomicAdd(&hcnt[NS + sd_[i]], 1);
  }
  int ek0 = b*(EEK/HB);
  for (int i = ek0 + t; i < ek0 + EEK/HB; i += 256) {
    atomicAdd(&hcnt[NS + es_[i]], 1);
    atomicAdd(&hcnt[NS + NE + ed_[i]], 1);
  }
  __syncthreads();
  int* pp = part + ((size_t)g*HB + b)*NNODE;
  for (int i = t; i < NNODE; i += 256) pp[i] = hcnt[i];
}

// thread-per-node partial-sum: cnt[g][n] = sum_b part[g][b][n]  (coalesced over n)
__global__ void k_sumpart(const int* __restrict__ part, int* __restrict__ cnt_all) {
  int idx = blockIdx.x*256 + threadIdx.x;
  if (idx >= 3*NNODE) return;
  int g = idx / NNODE, n = idx - g*NNODE;
  const int* pg = part + (size_t)g*HB*NNODE + n;
  int s = 0;
  #pragma unroll
  for (int b = 0; b < HB; b++) s += pg[(size_t)b*NNODE];
  cnt_all[idx] = s;
}

// per-graph single-block scan of cnt -> row_ptr (lightweight: 9 reads/thread)
__global__ void k_scan(const int* __restrict__ cnt_all, int* __restrict__ rp_all) {
  __shared__ int sums[1024];
  const int CH = (NNODE + 1023) / 1024;    // 9
  int g = blockIdx.x, t = threadIdx.x;
  const int* cnt = cnt_all + g*NNODE;
  int* row_ptr = rp_all + g*RP;
  int base = t*CH;
  int local[CH];
  int s = 0;
  for (int j = 0; j < CH; j++) {
    int v = (base + j < NNODE) ? cnt[base + j] : 0;
    local[j] = s; s += v;
  }
  sums[t] = s; __syncthreads();
  for (int off = 1; off < 1024; off <<= 1) {
    int v = (t >= off) ? sums[t - off] : 0;
    __syncthreads();
    sums[t] += v;
    __syncthreads();
  }
  int excl = (t == 0) ? 0 : sums[t - 1];
  for (int j = 0; j < CH; j++)
    if (base + j < NNODE) row_ptr[base + j] = excl + local[j];
  if (t == 1023) row_ptr[NNODE] = sums[1023];
}

// thread-per-node: emit per-block cursors boff[g][b][n] (coalesced over n)
__global__ void k_boff(const int* __restrict__ part, const int* __restrict__ rp_all,
                       int* __restrict__ boff) {
  int idx = blockIdx.x*256 + threadIdx.x;
  if (idx >= 3*NNODE) return;
  int g = idx / NNODE, n = idx - g*NNODE;
  const int* pg = part + (size_t)g*HB*NNODE + n;
  int* bg = boff + (size_t)g*HB*NNODE + n;
  int acc = rp_all[g*RP + n];
  #pragma unroll
  for (int b = 0; b < HB; b++) {
    bg[(size_t)b*NNODE] = acc;
    acc += pg[(size_t)b*NNODE];
  }
}

// scatter via LDS cursors initialized from boff (no global atomics); col stored ushort
__global__ __launch_bounds__(256)
void k_scatter(EdgePtrs ep, const int* __restrict__ boff, unsigned short* __restrict__ col_all) {
  __shared__ int cur[NNODE];      // 33 KB live cursors
  int g = blockIdx.y, b = blockIdx.x, t = threadIdx.x;
  const int* bg = boff + ((size_t)g*HB + b)*NNODE;
  for (int i = t; i < NNODE; i += 256) cur[i] = bg[i];
  __syncthreads();
  const int* ss_ = ep.s_src[g]; const int* sd_ = ep.s_dst[g];
  const int* es_ = ep.e_src[g]; const int* ed_ = ep.e_dst[g];
  unsigned short* col = col_all + (size_t)g*NCSR;
  int se0 = b*(ESE/HB);
  for (int i = se0 + t; i < se0 + ESE/HB; i += 256) {
    int s = ss_[i], d = NS + sd_[i];
    col[atomicAdd(&cur[s], 1)] = (unsigned short)d;
    col[atomicAdd(&cur[d], 1)] = (unsigned short)s;
  }
  int ek0 = b*(EEK/HB);
  for (int i = ek0 + t; i < ek0 + EEK/HB; i += 256) {
    int s = NS + es_[i], d = NS + NE + ed_[i];
    col[atomicAdd(&cur[s], 1)] = (unsigned short)d;
    col[atomicAdd(&cur[d], 1)] = (unsigned short)s;
  }
}

// ---------- transpose the 3 head weight matrices ----------
__global__ void k_tr(const float* __restrict__ pW1, const float* __restrict__ pW2,
                     const float* __restrict__ pW3, float* __restrict__ T) {
  __shared__ float tile[32][33];
  int m = blockIdx.z;
  const float* src = m == 0 ? pW1 : (m == 1 ? pW2 : pW3);
  float* dst = T + m*KD*KD;
  int bx = blockIdx.x*32, by = blockIdx.y*32;
  int tx = threadIdx.x, ty = threadIdx.y;   // block (32,8)
  for (int j = 0; j < 32; j += 8)
    tile[ty + j][tx] = src[(by + ty + j)*KD + bx + tx];
  __syncthreads();
  for (int j = 0; j < 32; j += 8)
    dst[(bx + ty + j)*KD + by + tx] = tile[tx][ty + j];
}

// ---------- register-blocked node GEMM ----------
// MODE 0: hb = bf16(inb@Wa) + fused ss/sd (v1=a_s, v2=a_d); bf16 input; 32 rows/block
// MODE 3: same epilogue, stages fp32 rows gathered from embedding tables; 32 rows/block
// MODE 4: fused head, 16 rows/block (512 blocks -> 2 blocks/CU): bs=g1[i1], be=g1[NS+i2];
//         P=sigm(bs@Wa), D=sigm(be@Wb), o=sigm((P-D)@Wc + v1);
//         out[row]=sum(o*v2[row,:])/sum(v2[row,:])
template<int MODE>
__global__ __launch_bounds__(256)
void k_ngemm(const unsigned short* __restrict__ inb,
             const float* __restrict__ Wa, const float* __restrict__ Wb,
             const float* __restrict__ Wc,
             const float* __restrict__ v1, const float* __restrict__ v2,
             float* __restrict__ out, unsigned short* __restrict__ hb,
             float* __restrict__ ss, float* __restrict__ sd,
             int nrows,
             const float* __restrict__ g1, const float* __restrict__ g2,
             const float* __restrict__ g3,
             const int* __restrict__ i1, const int* __restrict__ i2,
             const int* __restrict__ i3) {
  constexpr int ROWS = (MODE == 4) ? 16 : 32;   // rows per block
  constexpr int RPW  = ROWS/4;                  // rows per wave
  __shared__ float ers[ROWS][KD];
  __shared__ float xs[(MODE == 4) ? ROWS : 1][KD];
  int t = threadIdx.x;
  int row0 = blockIdx.x * ROWS;
  int w = t >> 6, c = t & 63;

  // ---- stage pass 1 ----
  for (int i = t; i < ROWS*KD; i += 256) {
    int r = i >> 7, k = i & 127;
    int gr = row0 + r;
    float val;
    if (MODE == 3) {
      const float* srow;
      if (gr < NS)           srow = g1 + (size_t)i1[gr]*KD;
      else if (gr < NS + NE) srow = g2 + (size_t)i2[gr - NS]*KD;
      else                   srow = g3 + (size_t)i3[gr - NS - NE]*KD;
      val = srow[k];
    } else if (MODE == 4) {
      val = g1[(size_t)i1[gr]*KD + k];
    } else {
      val = (gr < nrows) ? bf2f_(inb[(size_t)gr*KD + k]) : 0.f;
    }
    ers[r][k] = val;
  }
  __syncthreads();

  float acc0[RPW], acc1[RPW];
  #pragma unroll
  for (int r = 0; r < RPW; r++) { acc0[r] = 0.f; acc1[r] = 0.f; }
  #pragma unroll 2
  for (int kc = 0; kc < KD; kc += 4) {
    float wa[4], wb[4];
    #pragma unroll
    for (int j = 0; j < 4; j++) {
      wa[j] = Wa[(kc + j)*KD + c];
      wb[j] = Wa[(kc + j)*KD + c + 64];
    }
    #pragma unroll
    for (int r = 0; r < RPW; r++) {
      float4 e = *(const float4*)&ers[w*RPW + r][kc];   // wave-uniform broadcast read
      acc0[r] += e.x*wa[0] + e.y*wa[1] + e.z*wa[2] + e.w*wa[3];
      acc1[r] += e.x*wb[0] + e.y*wb[1] + e.z*wb[2] + e.w*wb[3];
    }
  }

  if (MODE == 0 || MODE == 3) {
    float as1 = v1[c], as2 = v1[c + 64], ad1 = v2[c], ad2 = v2[c + 64];
    #pragma unroll
    for (int r = 0; r < RPW; r++) {
      int gr = row0 + w*RPW + r;
      if (gr < nrows) {
        hb[(size_t)gr*KD + c]      = f2b_(acc0[r]);
        hb[(size_t)gr*KD + c + 64] = f2b_(acc1[r]);
      }
      float s = acc0[r]*as1 + acc1[r]*as2;
      float d = acc0[r]*ad1 + acc1[r]*ad2;
      #pragma unroll
      for (int off = 32; off; off >>= 1) { s += __shfl_xor(s, off); d += __shfl_xor(d, off); }
      if (c == 0 && gr < nrows) { ss[gr] = s; sd[gr] = d; }
    }
    return;
  }

  if (MODE == 4) {
    #pragma unroll
    for (int r = 0; r < RPW; r++) {
      xs[w*RPW + r][c]      = sigm_(acc0[r]);
      xs[w*RPW + r][c + 64] = sigm_(acc1[r]);
    }
    __syncthreads();   // all waves done reading ers (GEMM1)
    for (int i = t; i < ROWS*KD; i += 256) {
      int r = i >> 7, k = i & 127;
      int gr = row0 + r;
      ers[r][k] = g1[(size_t)(NS + i2[gr])*KD + k];
    }
    __syncthreads();
    #pragma unroll
    for (int r = 0; r < RPW; r++) { acc0[r] = 0.f; acc1[r] = 0.f; }
    #pragma unroll 2
    for (int kc = 0; kc < KD; kc += 4) {
      float wa[4], wb[4];
      #pragma unroll
      for (int j = 0; j < 4; j++) {
        wa[j] = Wb[(kc + j)*KD + c];
        wb[j] = Wb[(kc + j)*KD + c + 64];
      }
      #pragma unroll
      for (int r = 0; r < RPW; r++) {
        float4 e = *(const float4*)&ers[w*RPW + r][kc];
        acc0[r] += e.x*wa[0] + e.y*wa[1] + e.z*wa[2] + e.w*wa[3];
        acc1[r] += e.x*wb[0] + e.y*wb[1] + e.z*wb[2] + e.w*wb[3];
      }
    }
    #pragma unroll
    for (int r = 0; r < RPW; r++) {     // xs rows are wave-private
      xs[w*RPW + r][c]      -= sigm_(acc0[r]);
      xs[w*RPW + r][c + 64] -= sigm_(acc1[r]);
    }
    #pragma unroll
    for (int r = 0; r < RPW; r++) { acc0[r] = 0.f; acc1[r] = 0.f; }
    #pragma unroll 2
    for (int kc = 0; kc < KD; kc += 4) {
      float wa[4], wb[4];
      #pragma unroll
      for (int j = 0; j < 4; j++) {
        wa[j] = Wc[(kc + j)*KD + c];
        wb[j] = Wc[(kc + j)*KD + c + 64];
      }
      #pragma unroll
      for (int r = 0; r < RPW; r++) {
        float4 e = *(const float4*)&xs[w*RPW + r][kc];
        acc0[r] += e.x*wa[0] + e.y*wa[1] + e.z*wa[2] + e.w*wa[3];
        acc1[r] += e.x*wb[0] + e.y*wb[1] + e.z*wb[2] + e.w*wb[3];
      }
    }
    float b1 = v1[c], b2 = v1[c + 64];
    #pragma unroll
    for (int r = 0; r < RPW; r++) {
      int gr = row0 + w*RPW + r;
      float kr1 = v2[(size_t)gr*KD + c], kr2 = v2[(size_t)gr*KD + c + 64];
      float o1 = sigm_(acc0[r] + b1), o2 = sigm_(acc1[r] + b2);
      float num = o1*kr1 + o2*kr2, den = kr1 + kr2;
      #pragma unroll
      for (int off = 32; off; off >>= 1) { num += __shfl_xor(num, off); den += __shfl_xor(den, off); }
      if (c == 0) out[gr] = num/den;
    }
  }
}

// ---------- segment-softmax aggregation, 3 graphs batched ----------
// bf16 messages (256B rows): 4 edge-subgroups x 16 feature-lanes.
// ILP restructure: broadcast all 16 col-ids first, issue all 16 row loads
// (independent of the exp chain), then shuffle p and FMA.
__global__ __launch_bounds__(256)
void k_agg(const int* __restrict__ rp_all, const unsigned short* __restrict__ col_all,
           const unsigned short* __restrict__ hb_base, const float* __restrict__ ss,
           const float* __restrict__ sd, unsigned short* __restrict__ outb,
           float* __restrict__ out, unsigned short* __restrict__ Zo) {
  int gw = blockIdx.x*4 + (threadIdx.x >> 6);
  int lane = threadIdx.x & 63;
  if (gw >= 3*NNODE) return;
  int g = gw / NNODE;
  int node = gw - g*NNODE;
  bool layer2 = (Zo != nullptr);
  if (layer2 && node >= NS + NE) return;        // k rows unused after layer 2
  const int* rp = rp_all + g*RP;
  const unsigned short* cl = col_all + (size_t)g*NCSR;
  const unsigned short* hgb = layer2 ? hb_base + (size_t)g*NNODE*KD : hb_base;
  const float* ssg = layer2 ? ss + g*NNODE : ss;
  const float* sdg = layer2 ? sd + g*NNODE : sd;
  int e0 = rp[node], e1 = rp[node + 1];
  float sdv = sdg[node];
  int sub = lane >> 4;       // edge subgroup 0..3
  int fl  = lane & 15;       // feature lane: features fl*8 .. fl*8+7
  float l = 0.f;
  float A[8] = {0,0,0,0,0,0,0,0};
  for (int base = e0; base < e1; base += 64) {
    int e = base + lane;
    int cnt = e1 - base; if (cnt > 64) cnt = 64;
    bool act = lane < cnt;
    int o = act ? (int)cl[e] : 0;
    // broadcast col ids (independent of score chain)
    int ojs[16];
    #pragma unroll
    for (int j = 0; j < 16; j++) ojs[j] = __shfl(o, j*4 + sub);
    // issue all guarded row loads
    short8 mvs[16];
    #pragma unroll
    for (int j = 0; j < 16; j++)
      if (j*4 + sub < cnt)
        mvs[j] = *(const short8*)&hgb[(size_t)ojs[j]*KD + fl*8];
    // score chain overlaps with loads
    float p = act ? __expf(lrelu_(ssg[o] + sdv)) : 0.f;
    l += p;
    #pragma unroll
    for (int j = 0; j < 16; j++) {
      float pj = __shfl(p, j*4 + sub);
      if (j*4 + sub < cnt) {
        #pragma unroll
        for (int q = 0; q < 8; q++)
          A[q] += pj * bf2f_((unsigned short)mvs[j][q]);
      }
    }
  }
  #pragma unroll
  for (int off = 32; off; off >>= 1) l += __shfl_xor(l, off);
  #pragma unroll
  for (int q = 0; q < 8; q++) {
    A[q] += __shfl_xor(A[q], 16);
    A[q] += __shfl_xor(A[q], 32);
  }
  float inv = 1.f/(l + 1e-16f);
  float av[8];
  #pragma unroll
  for (int q = 0; q < 8; q++) av[q] = elu_(A[q]*inv);
  if (!layer2) {
    if (sub == 0) {
      short8 sv;
      #pragma unroll
      for (int q = 0; q < 8; q++) sv[q] = (short)f2b_(av[q]);
      *(short8*)&outb[(size_t)gw*KD + fl*8] = sv;
    }
    return;
  }
  if (g == 0) {
    if (sub == 0) {
      float* orow = &out[(size_t)node*KD + fl*8];
      *(float4*)orow       = make_float4(av[0], av[1], av[2], av[3]);
      *(float4*)(orow + 4) = make_float4(av[4], av[5], av[6], av[7]);
    }
  } else {
    float nrm = av[0]*av[0] + av[1]*av[1] + av[2]*av[2] + av[3]*av[3]
              + av[4]*av[4] + av[5]*av[5] + av[6]*av[6] + av[7]*av[7];
    #pragma unroll
    for (int off = 1; off <= 8; off <<= 1) nrm += __shfl_xor(nrm, off);
    float invn = 1.f/(sqrtf(nrm) + 1e-12f);
    if (sub == 0) {
      short8 sv;
      #pragma unroll
      for (int q = 0; q < 8; q++) sv[q] = (short)f2b_(av[q]*invn);
      *(short8*)&Zo[((size_t)(g - 1)*8192 + node)*KD + fl*8] = sv;
    }
  }
}

// ---------- bf16 MFMA similarity GEMM, atomic-free partial-sum epilogue ----------
// grid (32,32,2). rsp/csp: [2][64][NS] partials, unique writer per element.
__global__ __launch_bounds__(256)
void k_sim(const unsigned short* __restrict__ Z, float* __restrict__ rsp,
           float* __restrict__ csp, float* __restrict__ dg_all) {
  __shared__ unsigned short As[128*KD];   // 32 KB, row r: 16 groups of 8, group g at (g ^ (r&15))
  __shared__ unsigned short Bs[128*KD];   // 32 KB
  int z = blockIdx.z;
  int t = threadIdx.x;
  const unsigned short* Arow = Z + ((size_t)z*NS + (size_t)blockIdx.x*128)*KD;
  const unsigned short* Brow = Z + ((size_t)8192 + (size_t)z*NS + (size_t)blockIdx.y*128)*KD;
  #pragma unroll
  for (int j = 0; j < 8; j++) {
    int G = t + j*256;                     // linear 16B-group id, 0..2047
    int r = G >> 4, g = G & 15;
    int sw = g ^ (r & 15);
    *(float4*)&As[(r*16 + sw)*8] = *(const float4*)&Arow[(size_t)G*8];
    *(float4*)&Bs[(r*16 + sw)*8] = *(const float4*)&Brow[(size_t)G*8];
  }
  __syncthreads();
  int w = t >> 6, lane = t & 63;
  int rw = (w >> 1)*64, cw = (w & 1)*64;
  int m15 = lane & 15, quad = lane >> 4;
  float4_ acc[4][4] = {};
  #pragma unroll
  for (int kq = 0; kq < 4; kq++) {
    short8 a[4], b[4];
    int g = kq*4 + quad;
    #pragma unroll
    for (int mi = 0; mi < 4; mi++) {
      int r = rw + mi*16 + m15;
      a[mi] = *(const short8*)&As[(r*16 + (g ^ (r & 15)))*8];
    }
    #pragma unroll
    for (int ni = 0; ni < 4; ni++) {
      int r = cw + ni*16 + m15;
      b[ni] = *(const short8*)&Bs[(r*16 + (g ^ (r & 15)))*8];
    }
    #pragma unroll
    for (int mi = 0; mi < 4; mi++)
      #pragma unroll
      for (int ni = 0; ni < 4; ni++)
        acc[mi][ni] = __builtin_amdgcn_mfma_f32_16x16x32_bf16(a[mi], b[ni], acc[mi][ni], 0, 0, 0);
  }
  int i0 = blockIdx.x*128, j0 = blockIdx.y*128;
  float* diag = dg_all + z*NS;
  float* rrow = rsp + ((size_t)z*64 + blockIdx.y*2 + (w & 1))*NS;
  float* crow = csp + ((size_t)z*64 + blockIdx.x*2 + (w >> 1))*NS;
  float cs[4] = {0,0,0,0};
  #pragma unroll
  for (int mi = 0; mi < 4; mi++) {
    float rs[4] = {0,0,0,0};
    #pragma unroll
    for (int ni = 0; ni < 4; ni++) {
      #pragma unroll
      for (int reg = 0; reg < 4; reg++) {
        float sim2 = acc[mi][ni][reg]*2.0f;
        int gi = i0 + rw + mi*16 + quad*4 + reg;     // C/D: row=(lane>>4)*4+reg
        int gj = j0 + cw + ni*16 + m15;              //      col=lane&15
        if (gi == gj) diag[gi] = sim2;
        float e = __expf(sim2);
        rs[reg] += e; cs[ni] += e;
      }
    }
    #pragma unroll
    for (int reg = 0; reg < 4; reg++) {
      float v = rs[reg];
      v += __shfl_xor(v, 1); v += __shfl_xor(v, 2);
      v += __shfl_xor(v, 4); v += __shfl_xor(v, 8);
      if (m15 == 0) rrow[i0 + rw + mi*16 + quad*4 + reg] = v;
    }
  }
  #pragma unroll
  for (int ni = 0; ni < 4; ni++) {
    float v = cs[ni];
    v += __shfl_xor(v, 16); v += __shfl_xor(v, 32);
    if (quad == 0) crow[j0 + cw + ni*16 + m15] = v;
  }
}

// reduce partials -> per-block loss partial (grid (16,2))
__global__ void k_lred(const float* __restrict__ rsp, const float* __restrict__ csp,
                       const float* __restrict__ dg_all, float* __restrict__ pbuf) {
  __shared__ float red[256];
  int z = blockIdx.y;
  int i = blockIdx.x*256 + threadIdx.x;
  float rs = 0.f, cs = 0.f;
  for (int s = 0; s < 64; s++) {
    rs += rsp[((size_t)z*64 + s)*NS + i];
    cs += csp[((size_t)z*64 + s)*NS + i];
  }
  float v = logf(rs) + logf(cs) - 2.f*dg_all[z*NS + i];
  red[threadIdx.x] = v; __syncthreads();
  for (int off = 128; off; off >>= 1) {
    if (threadIdx.x < off) red[threadIdx.x] += red[threadIdx.x + off];
    __syncthreads();
  }
  if (threadIdx.x == 0) pbuf[z*16 + blockIdx.x] = red[0];
}

__global__ void k_lfin(const float* __restrict__ pbuf, float* __restrict__ out) {
  int t = threadIdx.x;
  float v = (t < 32) ? pbuf[t] : 0.f;
  #pragma unroll
  for (int off = 32; off; off >>= 1) v += __shfl_xor(v, off);
  if (t == 0) out[BQ] = 0.1f*v/(float)NS;
}

extern "C" void kernel_launch(void* const* d_in, const int* in_sizes, int n_in,
                              void* d_out, int out_size, void* d_ws, size_t ws_size,
                              hipStream_t stream) {
  const float* E_stu  = (const float*)d_in[0];
  const float* E_exer = (const float*)d_in[1];
  const float* E_k    = (const float*)d_in[2];
  const float* W1  = (const float*)d_in[3];
  const float* a1s = (const float*)d_in[4];
  const float* a1d = (const float*)d_in[5];
  const float* W2  = (const float*)d_in[6];
  const float* a2s = (const float*)d_in[7];
  const float* a2d = (const float*)d_in[8];
  const float* pW1 = (const float*)d_in[9];
  const float* pW2 = (const float*)d_in[10];
  const float* pW3 = (const float*)d_in[11];
  const float* pb3 = (const float*)d_in[12];
  const float* kn_r = (const float*)d_in[13];
  const int* stu_ids  = (const int*)d_in[14];
  const int* exer_ids = (const int*)d_in[15];
  const int* k_ids    = (const int*)d_in[16];
  EdgePtrs ep;
  for (int g = 0; g < 3; g++) {
    ep.s_src[g] = (const int*)d_in[17 + g*4];
    ep.s_dst[g] = (const int*)d_in[18 + g*4];
    ep.e_src[g] = (const int*)d_in[19 + g*4];
    ep.e_dst[g] = (const int*)d_in[20 + g*4];
  }
  const int* stu_index  = (const int*)d_in[29];
  const int* exer_index = (const int*)d_in[30];
  float* out = (float*)d_out;   // [0..8191] predictions, [8192] closs

  // ---- workspace carve ----
  char* p = (char*)d_ws;
  auto carve = [&](size_t bytes) -> char* {
    char* r = p; p += (bytes + 255) & ~(size_t)255; return r;
  };
  const size_t NODE_F = (size_t)NNODE*KD;
  float* ssb = (float*)carve((size_t)8*NNODE*4);
  float* ss0 = ssb,            *sd0 = ssb + NNODE;
  float* ss3 = ssb + 2*NNODE,  *sd3 = ssb + 5*NNODE;
  unsigned short* hb0 = (unsigned short*)carve(NODE_F*2);        // layer-1 h (shared)
  unsigned short* hb3 = (unsigned short*)carve(3*NODE_F*2);      // layer-2 h x3
  // time-multiplexed: CSR partials (6.4 MB) -> layer-1 agg bf16 out (6.4 MB)
  char* Creg = carve((size_t)8*HB*NNODE*4);
  int*   part = (int*)Creg;                       // part[3][HB][NNODE]
  int*   boff = (int*)Creg + (size_t)3*HB*NNODE;  // boff[3][HB][NNODE]
  unsigned short* etb = (unsigned short*)Creg;    // layer-1 agg out, bf16 [3*NNODE][KD]
  float* eoutAll = (float*)carve((size_t)(NS + NE)*KD*4);        // main-graph layer-2 out
  int* cnt_all = (int*)carve((size_t)3*NNODE*4);
  int* rp_all  = (int*)carve((size_t)3*RP*4);
  unsigned short* col_all = (unsigned short*)carve((size_t)3*NCSR*2);
  float* pWT = (float*)carve((size_t)3*KD*KD*4);
  float* pW1T = pWT, *pW2T = pWT + KD*KD, *pW3T = pWT + 2*KD*KD;
  float* rsp = (float*)carve((size_t)2*64*NS*4);   // rowsum partials
  float* csp = (float*)carve((size_t)2*64*NS*4);   // colsum partials
  float* dg_all = (float*)carve((size_t)2*NS*4);
  float* pbuf = (float*)carve(64*4);
  unsigned short* Z = (unsigned short*)carve((size_t)2*8192*KD*2);  // bf16 Z1|Z2

  // ---- CSR build (atomic-free, all stages parallel) + weight transpose ----
  k_hist<<<dim3(HB, 3), 256, 0, stream>>>(ep, part);
  k_sumpart<<<(3*NNODE + 255)/256, 256, 0, stream>>>(part, cnt_all);
  k_scan<<<3, 1024, 0, stream>>>(cnt_all, rp_all);
  k_boff<<<(3*NNODE + 255)/256, 256, 0, stream>>>(part, rp_all, boff);
  k_scatter<<<dim3(HB, 3), 256, 0, stream>>>(ep, boff, col_all);
  k_tr<<<dim3(4, 4, 3), dim3(32, 8), 0, stream>>>(pW1, pW2, pW3, pWT);

  // ---- GAT layer 1 (h shared across graphs; embedding gather fused; bf16 h) ----
  k_ngemm<3><<<NNODE/32, 256, 0, stream>>>(nullptr, W1, nullptr, nullptr, a1s, a1d,
                                           nullptr, hb0, ss0, sd0, NNODE,
                                           E_stu, E_exer, E_k, stu_ids, exer_ids, k_ids);
  k_agg<<<3*NNODE/4, 256, 0, stream>>>(rp_all, col_all, hb0, ss0, sd0, etb, nullptr, nullptr);

  // ---- GAT layer 2 (bf16 input) ----
  k_ngemm<0><<<3*NNODE/32, 256, 0, stream>>>(etb, W2, nullptr, nullptr, a2s, a2d,
                                             nullptr, hb3, ss3, sd3, 3*NNODE,
                                             nullptr, nullptr, nullptr, nullptr, nullptr, nullptr);
  k_agg<<<3*NNODE/4, 256, 0, stream>>>(rp_all, col_all, hb3, ss3, sd3, nullptr, eoutAll, Z);

  // ---- contrastive loss (bf16 MFMA sim, atomic-free epilogue) ----
  k_sim<<<dim3(32, 32, 2), 256, 0, stream>>>(Z, rsp, csp, dg_all);
  k_lred<<<dim3(16, 2), 256, 0, stream>>>(rsp, csp, dg_all, pbuf);
  k_lfin<<<1, 64, 0, stream>>>(pbuf, out);

  // ---- prediction head (fully fused, 16 rows/block -> 512 blocks) ----
  k_ngemm<4><<<BQ/16, 256, 0, stream>>>(nullptr, pW1T, pW2T, pW3T, pb3, kn_r,
                                        out, nullptr, nullptr, nullptr, BQ,
                                        eoutAll, nullptr, nullptr, stu_index, exer_index, nullptr);
}

// Round 10
// 334.845 us; speedup vs baseline: 1.1873x; 1.1873x over previous
//
#include <hip/hip_runtime.h>
#include <hip/hip_bf16.h>
#include <math.h>

#define KD 128
#define NS 4096
#define NE 4096
#define NK 128
#define NNODE (NS + NE + NK)      // 8320
#define ESE 131072
#define EEK 16384
#define NCSR (2*ESE + 2*EEK)      // 294912
#define BQ 8192
#define RP (NNODE + 1)
#define HB 32                     // CSR-build blocks per graph

typedef __attribute__((ext_vector_type(8))) short short8;   // 8 bf16 (4 VGPRs)
typedef __attribute__((ext_vector_type(4))) float float4_;  // 4 fp32 acc

__device__ __forceinline__ float lrelu_(float x){ return x >= 0.f ? x : 0.2f*x; }
__device__ __forceinline__ float elu_(float x){ return x > 0.f ? x : __expf(x) - 1.f; }
__device__ __forceinline__ float sigm_(float x){ return 1.f/(1.f + __expf(-x)); }
__device__ __forceinline__ float bf2f_(unsigned short u){
  union { unsigned int i; float f; } v; v.i = ((unsigned int)u) << 16; return v.f;
}
__device__ __forceinline__ unsigned short f2b_(float x){
  __hip_bfloat16 b = __float2bfloat16(x); return *(unsigned short*)&b;
}

struct EdgePtrs { const int* s_src[3]; const int* s_dst[3]; const int* e_src[3]; const int* e_dst[3]; };

// ---------- CSR build: LDS histogram -> per-block partial counts (no global atomics) ----------
__global__ __launch_bounds__(256)
void k_hist(EdgePtrs ep, int* __restrict__ part) {
  __shared__ int hcnt[NNODE];     // 33 KB
  int g = blockIdx.y, b = blockIdx.x, t = threadIdx.x;
  for (int i = t; i < NNODE; i += 256) hcnt[i] = 0;
  __syncthreads();
  const int* ss_ = ep.s_src[g]; const int* sd_ = ep.s_dst[g];
  const int* es_ = ep.e_src[g]; const int* ed_ = ep.e_dst[g];
  int se0 = b*(ESE/HB);
  for (int i = se0 + t; i < se0 + ESE/HB; i += 256) {
    atomicAdd(&hcnt[ss_[i]], 1);
    atomicAdd(&hcnt[NS + sd_[i]], 1);
  }
  int ek0 = b*(EEK/HB);
  for (int i = ek0 + t; i < ek0 + EEK/HB; i += 256) {
    atomicAdd(&hcnt[NS + es_[i]], 1);
    atomicAdd(&hcnt[NS + NE + ed_[i]], 1);
  }
  __syncthreads();
  int* pp = part + ((size_t)g*HB + b)*NNODE;
  for (int i = t; i < NNODE; i += 256) pp[i] = hcnt[i];
}

// thread-per-node partial-sum: cnt[g][n] = sum_b part[g][b][n]  (coalesced over n)
__global__ void k_sumpart(const int* __restrict__ part, int* __restrict__ cnt_all) {
  int idx = blockIdx.x*256 + threadIdx.x;
  if (idx >= 3*NNODE) return;
  int g = idx / NNODE, n = idx - g*NNODE;
  const int* pg = part + (size_t)g*HB*NNODE + n;
  int s = 0;
  #pragma unroll
  for (int b = 0; b < HB; b++) s += pg[(size_t)b*NNODE];
  cnt_all[idx] = s;
}

// per-graph single-block scan of cnt -> row_ptr (lightweight: 9 reads/thread)
__global__ void k_scan(const int* __restrict__ cnt_all, int* __restrict__ rp_all) {
  __shared__ int sums[1024];
  const int CH = (NNODE + 1023) / 1024;    // 9
  int g = blockIdx.x, t = threadIdx.x;
  const int* cnt = cnt_all + g*NNODE;
  int* row_ptr = rp_all + g*RP;
  int base = t*CH;
  int local[CH];
  int s = 0;
  for (int j = 0; j < CH; j++) {
    int v = (base + j < NNODE) ? cnt[base + j] : 0;
    local[j] = s; s += v;
  }
  sums[t] = s; __syncthreads();
  for (int off = 1; off < 1024; off <<= 1) {
    int v = (t >= off) ? sums[t - off] : 0;
    __syncthreads();
    sums[t] += v;
    __syncthreads();
  }
  int excl = (t == 0) ? 0 : sums[t - 1];
  for (int j = 0; j < CH; j++)
    if (base + j < NNODE) row_ptr[base + j] = excl + local[j];
  if (t == 1023) row_ptr[NNODE] = sums[1023];
}

// thread-per-node: emit per-block cursors boff[g][b][n] (coalesced over n)
__global__ void k_boff(const int* __restrict__ part, const int* __restrict__ rp_all,
                       int* __restrict__ boff) {
  int idx = blockIdx.x*256 + threadIdx.x;
  if (idx >= 3*NNODE) return;
  int g = idx / NNODE, n = idx - g*NNODE;
  const int* pg = part + (size_t)g*HB*NNODE + n;
  int* bg = boff + (size_t)g*HB*NNODE + n;
  int acc = rp_all[g*RP + n];
  #pragma unroll
  for (int b = 0; b < HB; b++) {
    bg[(size_t)b*NNODE] = acc;
    acc += pg[(size_t)b*NNODE];
  }
}

// scatter via LDS cursors initialized from boff (no global atomics); col stored ushort
__global__ __launch_bounds__(256)
void k_scatter(EdgePtrs ep, const int* __restrict__ boff, unsigned short* __restrict__ col_all) {
  __shared__ int cur[NNODE];      // 33 KB live cursors
  int g = blockIdx.y, b = blockIdx.x, t = threadIdx.x;
  const int* bg = boff + ((size_t)g*HB + b)*NNODE;
  for (int i = t; i < NNODE; i += 256) cur[i] = bg[i];
  __syncthreads();
  const int* ss_ = ep.s_src[g]; const int* sd_ = ep.s_dst[g];
  const int* es_ = ep.e_src[g]; const int* ed_ = ep.e_dst[g];
  unsigned short* col = col_all + (size_t)g*NCSR;
  int se0 = b*(ESE/HB);
  for (int i = se0 + t; i < se0 + ESE/HB; i += 256) {
    int s = ss_[i], d = NS + sd_[i];
    col[atomicAdd(&cur[s], 1)] = (unsigned short)d;
    col[atomicAdd(&cur[d], 1)] = (unsigned short)s;
  }
  int ek0 = b*(EEK/HB);
  for (int i = ek0 + t; i < ek0 + EEK/HB; i += 256) {
    int s = NS + es_[i], d = NS + NE + ed_[i];
    col[atomicAdd(&cur[s], 1)] = (unsigned short)d;
    col[atomicAdd(&cur[d], 1)] = (unsigned short)s;
  }
}

// ---------- transpose the 3 head weight matrices ----------
__global__ void k_tr(const float* __restrict__ pW1, const float* __restrict__ pW2,
                     const float* __restrict__ pW3, float* __restrict__ T) {
  __shared__ float tile[32][33];
  int m = blockIdx.z;
  const float* src = m == 0 ? pW1 : (m == 1 ? pW2 : pW3);
  float* dst = T + m*KD*KD;
  int bx = blockIdx.x*32, by = blockIdx.y*32;
  int tx = threadIdx.x, ty = threadIdx.y;   // block (32,8)
  for (int j = 0; j < 32; j += 8)
    tile[ty + j][tx] = src[(by + ty + j)*KD + bx + tx];
  __syncthreads();
  for (int j = 0; j < 32; j += 8)
    dst[(bx + ty + j)*KD + by + tx] = tile[tx][ty + j];
}

// ---------- register-blocked node GEMM ----------
// MODE 0: hb = bf16(inb@Wa) + fused ss/sd (v1=a_s, v2=a_d); bf16 input; 32 rows/block
// MODE 3: same epilogue, stages fp32 rows gathered from embedding tables; 32 rows/block
// MODE 4: fused head, 16 rows/block (512 blocks -> 2 blocks/CU): bs=g1[i1], be=g1[NS+i2];
//         P=sigm(bs@Wa), D=sigm(be@Wb), o=sigm((P-D)@Wc + v1);
//         out[row]=sum(o*v2[row,:])/sum(v2[row,:])
template<int MODE>
__global__ __launch_bounds__(256)
void k_ngemm(const unsigned short* __restrict__ inb,
             const float* __restrict__ Wa, const float* __restrict__ Wb,
             const float* __restrict__ Wc,
             const float* __restrict__ v1, const float* __restrict__ v2,
             float* __restrict__ out, unsigned short* __restrict__ hb,
             float* __restrict__ ss, float* __restrict__ sd,
             int nrows,
             const float* __restrict__ g1, const float* __restrict__ g2,
             const float* __restrict__ g3,
             const int* __restrict__ i1, const int* __restrict__ i2,
             const int* __restrict__ i3) {
  constexpr int ROWS = (MODE == 4) ? 16 : 32;   // rows per block
  constexpr int RPW  = ROWS/4;                  // rows per wave
  __shared__ float ers[ROWS][KD];
  __shared__ float xs[(MODE == 4) ? ROWS : 1][KD];
  int t = threadIdx.x;
  int row0 = blockIdx.x * ROWS;
  int w = t >> 6, c = t & 63;

  // ---- stage pass 1 ----
  for (int i = t; i < ROWS*KD; i += 256) {
    int r = i >> 7, k = i & 127;
    int gr = row0 + r;
    float val;
    if (MODE == 3) {
      const float* srow;
      if (gr < NS)           srow = g1 + (size_t)i1[gr]*KD;
      else if (gr < NS + NE) srow = g2 + (size_t)i2[gr - NS]*KD;
      else                   srow = g3 + (size_t)i3[gr - NS - NE]*KD;
      val = srow[k];
    } else if (MODE == 4) {
      val = g1[(size_t)i1[gr]*KD + k];
    } else {
      val = (gr < nrows) ? bf2f_(inb[(size_t)gr*KD + k]) : 0.f;
    }
    ers[r][k] = val;
  }
  __syncthreads();

  float acc0[RPW], acc1[RPW];
  #pragma unroll
  for (int r = 0; r < RPW; r++) { acc0[r] = 0.f; acc1[r] = 0.f; }
  #pragma unroll 2
  for (int kc = 0; kc < KD; kc += 4) {
    float wa[4], wb[4];
    #pragma unroll
    for (int j = 0; j < 4; j++) {
      wa[j] = Wa[(kc + j)*KD + c];
      wb[j] = Wa[(kc + j)*KD + c + 64];
    }
    #pragma unroll
    for (int r = 0; r < RPW; r++) {
      float4 e = *(const float4*)&ers[w*RPW + r][kc];   // wave-uniform broadcast read
      acc0[r] += e.x*wa[0] + e.y*wa[1] + e.z*wa[2] + e.w*wa[3];
      acc1[r] += e.x*wb[0] + e.y*wb[1] + e.z*wb[2] + e.w*wb[3];
    }
  }

  if (MODE == 0 || MODE == 3) {
    float as1 = v1[c], as2 = v1[c + 64], ad1 = v2[c], ad2 = v2[c + 64];
    #pragma unroll
    for (int r = 0; r < RPW; r++) {
      int gr = row0 + w*RPW + r;
      if (gr < nrows) {
        hb[(size_t)gr*KD + c]      = f2b_(acc0[r]);
        hb[(size_t)gr*KD + c + 64] = f2b_(acc1[r]);
      }
      float s = acc0[r]*as1 + acc1[r]*as2;
      float d = acc0[r]*ad1 + acc1[r]*ad2;
      #pragma unroll
      for (int off = 32; off; off >>= 1) { s += __shfl_xor(s, off); d += __shfl_xor(d, off); }
      if (c == 0 && gr < nrows) { ss[gr] = s; sd[gr] = d; }
    }
    return;
  }

  if (MODE == 4) {
    #pragma unroll
    for (int r = 0; r < RPW; r++) {
      xs[w*RPW + r][c]      = sigm_(acc0[r]);
      xs[w*RPW + r][c + 64] = sigm_(acc1[r]);
    }
    __syncthreads();   // all waves done reading ers (GEMM1)
    for (int i = t; i < ROWS*KD; i += 256) {
      int r = i >> 7, k = i & 127;
      int gr = row0 + r;
      ers[r][k] = g1[(size_t)(NS + i2[gr])*KD + k];
    }
    __syncthreads();
    #pragma unroll
    for (int r = 0; r < RPW; r++) { acc0[r] = 0.f; acc1[r] = 0.f; }
    #pragma unroll 2
    for (int kc = 0; kc < KD; kc += 4) {
      float wa[4], wb[4];
      #pragma unroll
      for (int j = 0; j < 4; j++) {
        wa[j] = Wb[(kc + j)*KD + c];
        wb[j] = Wb[(kc + j)*KD + c + 64];
      }
      #pragma unroll
      for (int r = 0; r < RPW; r++) {
        float4 e = *(const float4*)&ers[w*RPW + r][kc];
        acc0[r] += e.x*wa[0] + e.y*wa[1] + e.z*wa[2] + e.w*wa[3];
        acc1[r] += e.x*wb[0] + e.y*wb[1] + e.z*wb[2] + e.w*wb[3];
      }
    }
    #pragma unroll
    for (int r = 0; r < RPW; r++) {     // xs rows are wave-private
      xs[w*RPW + r][c]      -= sigm_(acc0[r]);
      xs[w*RPW + r][c + 64] -= sigm_(acc1[r]);
    }
    #pragma unroll
    for (int r = 0; r < RPW; r++) { acc0[r] = 0.f; acc1[r] = 0.f; }
    #pragma unroll 2
    for (int kc = 0; kc < KD; kc += 4) {
      float wa[4], wb[4];
      #pragma unroll
      for (int j = 0; j < 4; j++) {
        wa[j] = Wc[(kc + j)*KD + c];
        wb[j] = Wc[(kc + j)*KD + c + 64];
      }
      #pragma unroll
      for (int r = 0; r < RPW; r++) {
        float4 e = *(const float4*)&xs[w*RPW + r][kc];
        acc0[r] += e.x*wa[0] + e.y*wa[1] + e.z*wa[2] + e.w*wa[3];
        acc1[r] += e.x*wb[0] + e.y*wb[1] + e.z*wb[2] + e.w*wb[3];
      }
    }
    float b1 = v1[c], b2 = v1[c + 64];
    #pragma unroll
    for (int r = 0; r < RPW; r++) {
      int gr = row0 + w*RPW + r;
      float kr1 = v2[(size_t)gr*KD + c], kr2 = v2[(size_t)gr*KD + c + 64];
      float o1 = sigm_(acc0[r] + b1), o2 = sigm_(acc1[r] + b2);
      float num = o1*kr1 + o2*kr2, den = kr1 + kr2;
      #pragma unroll
      for (int off = 32; off; off >>= 1) { num += __shfl_xor(num, off); den += __shfl_xor(den, off); }
      if (c == 0) out[gr] = num/den;
    }
  }
}

// ---------- segment-softmax aggregation, 3 graphs batched (R7 body: low-VGPR) ----------
// bf16 messages (256B rows): 4 edge-subgroups x 16 feature-lanes, one 16B load
// per lane per edge. Single-pass softmax (scores bounded).
__global__ __launch_bounds__(256)
void k_agg(const int* __restrict__ rp_all, const unsigned short* __restrict__ col_all,
           const unsigned short* __restrict__ hb_base, const float* __restrict__ ss,
           const float* __restrict__ sd, unsigned short* __restrict__ outb,
           float* __restrict__ out, unsigned short* __restrict__ Zo) {
  int gw = blockIdx.x*4 + (threadIdx.x >> 6);
  int lane = threadIdx.x & 63;
  if (gw >= 3*NNODE) return;
  int g = gw / NNODE;
  int node = gw - g*NNODE;
  bool layer2 = (Zo != nullptr);
  if (layer2 && node >= NS + NE) return;        // k rows unused after layer 2
  const int* rp = rp_all + g*RP;
  const unsigned short* cl = col_all + (size_t)g*NCSR;
  const unsigned short* hgb = layer2 ? hb_base + (size_t)g*NNODE*KD : hb_base;
  const float* ssg = layer2 ? ss + g*NNODE : ss;
  const float* sdg = layer2 ? sd + g*NNODE : sd;
  int e0 = rp[node], e1 = rp[node + 1];
  float sdv = sdg[node];
  int sub = lane >> 4;       // edge subgroup 0..3
  int fl  = lane & 15;       // feature lane: features fl*8 .. fl*8+7
  float l = 0.f;
  float A[8] = {0,0,0,0,0,0,0,0};
  for (int base = e0; base < e1; base += 64) {
    int e = base + lane;
    float p = 0.f; int o = 0;
    if (e < e1) { o = cl[e]; p = __expf(lrelu_(ssg[o] + sdv)); }
    l += p;
    int cnt = min(64, e1 - base);
    #pragma unroll 4
    for (int j = 0; j*4 < cnt; j++) {
      int idx = j*4 + sub;
      float pj = __shfl(p, idx);
      int oj = __shfl(o, idx);
      if (idx < cnt) {
        short8 mv = *(const short8*)&hgb[(size_t)oj*KD + fl*8];   // 16B = 8 bf16
        #pragma unroll
        for (int q = 0; q < 8; q++)
          A[q] += pj * bf2f_((unsigned short)mv[q]);
      }
    }
  }
  #pragma unroll
  for (int off = 32; off; off >>= 1) l += __shfl_xor(l, off);
  #pragma unroll
  for (int q = 0; q < 8; q++) {
    A[q] += __shfl_xor(A[q], 16);
    A[q] += __shfl_xor(A[q], 32);
  }
  float inv = 1.f/(l + 1e-16f);
  float av[8];
  #pragma unroll
  for (int q = 0; q < 8; q++) av[q] = elu_(A[q]*inv);
  if (!layer2) {
    if (sub == 0) {
      short8 sv;
      #pragma unroll
      for (int q = 0; q < 8; q++) sv[q] = (short)f2b_(av[q]);
      *(short8*)&outb[(size_t)gw*KD + fl*8] = sv;
    }
    return;
  }
  if (g == 0) {
    if (sub == 0) {
      float* orow = &out[(size_t)node*KD + fl*8];
      *(float4*)orow       = make_float4(av[0], av[1], av[2], av[3]);
      *(float4*)(orow + 4) = make_float4(av[4], av[5], av[6], av[7]);
    }
  } else {
    float nrm = av[0]*av[0] + av[1]*av[1] + av[2]*av[2] + av[3]*av[3]
              + av[4]*av[4] + av[5]*av[5] + av[6]*av[6] + av[7]*av[7];
    #pragma unroll
    for (int off = 1; off <= 8; off <<= 1) nrm += __shfl_xor(nrm, off);
    float invn = 1.f/(sqrtf(nrm) + 1e-12f);
    if (sub == 0) {
      short8 sv;
      #pragma unroll
      for (int q = 0; q < 8; q++) sv[q] = (short)f2b_(av[q]*invn);
      *(short8*)&Zo[((size_t)(g - 1)*8192 + node)*KD + fl*8] = sv;
    }
  }
}

// ---------- bf16 MFMA similarity GEMM, atomic-free partial-sum epilogue ----------
// grid (32,32,2). rsp/csp: [2][64][NS] partials, unique writer per element.
__global__ __launch_bounds__(256)
void k_sim(const unsigned short* __restrict__ Z, float* __restrict__ rsp,
           float* __restrict__ csp, float* __restrict__ dg_all) {
  __shared__ unsigned short As[128*KD];   // 32 KB, row r: 16 groups of 8, group g at (g ^ (r&15))
  __shared__ unsigned short Bs[128*KD];   // 32 KB
  int z = blockIdx.z;
  int t = threadIdx.x;
  const unsigned short* Arow = Z + ((size_t)z*NS + (size_t)blockIdx.x*128)*KD;
  const unsigned short* Brow = Z + ((size_t)8192 + (size_t)z*NS + (size_t)blockIdx.y*128)*KD;
  #pragma unroll
  for (int j = 0; j < 8; j++) {
    int G = t + j*256;                     // linear 16B-group id, 0..2047
    int r = G >> 4, g = G & 15;
    int sw = g ^ (r & 15);
    *(float4*)&As[(r*16 + sw)*8] = *(const float4*)&Arow[(size_t)G*8];
    *(float4*)&Bs[(r*16 + sw)*8] = *(const float4*)&Brow[(size_t)G*8];
  }
  __syncthreads();
  int w = t >> 6, lane = t & 63;
  int rw = (w >> 1)*64, cw = (w & 1)*64;
  int m15 = lane & 15, quad = lane >> 4;
  float4_ acc[4][4] = {};
  #pragma unroll
  for (int kq = 0; kq < 4; kq++) {
    short8 a[4], b[4];
    int g = kq*4 + quad;
    #pragma unroll
    for (int mi = 0; mi < 4; mi++) {
      int r = rw + mi*16 + m15;
      a[mi] = *(const short8*)&As[(r*16 + (g ^ (r & 15)))*8];
    }
    #pragma unroll
    for (int ni = 0; ni < 4; ni++) {
      int r = cw + ni*16 + m15;
      b[ni] = *(const short8*)&Bs[(r*16 + (g ^ (r & 15)))*8];
    }
    #pragma unroll
    for (int mi = 0; mi < 4; mi++)
      #pragma unroll
      for (int ni = 0; ni < 4; ni++)
        acc[mi][ni] = __builtin_amdgcn_mfma_f32_16x16x32_bf16(a[mi], b[ni], acc[mi][ni], 0, 0, 0);
  }
  int i0 = blockIdx.x*128, j0 = blockIdx.y*128;
  float* diag = dg_all + z*NS;
  float* rrow = rsp + ((size_t)z*64 + blockIdx.y*2 + (w & 1))*NS;
  float* crow = csp + ((size_t)z*64 + blockIdx.x*2 + (w >> 1))*NS;
  float cs[4] = {0,0,0,0};
  #pragma unroll
  for (int mi = 0; mi < 4; mi++) {
    float rs[4] = {0,0,0,0};
    #pragma unroll
    for (int ni = 0; ni < 4; ni++) {
      #pragma unroll
      for (int reg = 0; reg < 4; reg++) {
        float sim2 = acc[mi][ni][reg]*2.0f;
        int gi = i0 + rw + mi*16 + quad*4 + reg;     // C/D: row=(lane>>4)*4+reg
        int gj = j0 + cw + ni*16 + m15;              //      col=lane&15
        if (gi == gj) diag[gi] = sim2;
        float e = __expf(sim2);
        rs[reg] += e; cs[ni] += e;
      }
    }
    #pragma unroll
    for (int reg = 0; reg < 4; reg++) {
      float v = rs[reg];
      v += __shfl_xor(v, 1); v += __shfl_xor(v, 2);
      v += __shfl_xor(v, 4); v += __shfl_xor(v, 8);
      if (m15 == 0) rrow[i0 + rw + mi*16 + quad*4 + reg] = v;
    }
  }
  #pragma unroll
  for (int ni = 0; ni < 4; ni++) {
    float v = cs[ni];
    v += __shfl_xor(v, 16); v += __shfl_xor(v, 32);
    if (quad == 0) crow[j0 + cw + ni*16 + m15] = v;
  }
}

// reduce partials -> per-block loss partial (grid (16,2))
__global__ void k_lred(const float* __restrict__ rsp, const float* __restrict__ csp,
                       const float* __restrict__ dg_all, float* __restrict__ pbuf) {
  __shared__ float red[256];
  int z = blockIdx.y;
  int i = blockIdx.x*256 + threadIdx.x;
  float rs = 0.f, cs = 0.f;
  for (int s = 0; s < 64; s++) {
    rs += rsp[((size_t)z*64 + s)*NS + i];
    cs += csp[((size_t)z*64 + s)*NS + i];
  }
  float v = logf(rs) + logf(cs) - 2.f*dg_all[z*NS + i];
  red[threadIdx.x] = v; __syncthreads();
  for (int off = 128; off; off >>= 1) {
    if (threadIdx.x < off) red[threadIdx.x] += red[threadIdx.x + off];
    __syncthreads();
  }
  if (threadIdx.x == 0) pbuf[z*16 + blockIdx.x] = red[0];
}

__global__ void k_lfin(const float* __restrict__ pbuf, float* __restrict__ out) {
  int t = threadIdx.x;
  float v = (t < 32) ? pbuf[t] : 0.f;
  #pragma unroll
  for (int off = 32; off; off >>= 1) v += __shfl_xor(v, off);
  if (t == 0) out[BQ] = 0.1f*v/(float)NS;
}

extern "C" void kernel_launch(void* const* d_in, const int* in_sizes, int n_in,
                              void* d_out, int out_size, void* d_ws, size_t ws_size,
                              hipStream_t stream) {
  const float* E_stu  = (const float*)d_in[0];
  const float* E_exer = (const float*)d_in[1];
  const float* E_k    = (const float*)d_in[2];
  const float* W1  = (const float*)d_in[3];
  const float* a1s = (const float*)d_in[4];
  const float* a1d = (const float*)d_in[5];
  const float* W2  = (const float*)d_in[6];
  const float* a2s = (const float*)d_in[7];
  const float* a2d = (const float*)d_in[8];
  const float* pW1 = (const float*)d_in[9];
  const float* pW2 = (const float*)d_in[10];
  const float* pW3 = (const float*)d_in[11];
  const float* pb3 = (const float*)d_in[12];
  const float* kn_r = (const float*)d_in[13];
  const int* stu_ids  = (const int*)d_in[14];
  const int* exer_ids = (const int*)d_in[15];
  const int* k_ids    = (const int*)d_in[16];
  EdgePtrs ep;
  for (int g = 0; g < 3; g++) {
    ep.s_src[g] = (const int*)d_in[17 + g*4];
    ep.s_dst[g] = (const int*)d_in[18 + g*4];
    ep.e_src[g] = (const int*)d_in[19 + g*4];
    ep.e_dst[g] = (const int*)d_in[20 + g*4];
  }
  const int* stu_index  = (const int*)d_in[29];
  const int* exer_index = (const int*)d_in[30];
  float* out = (float*)d_out;   // [0..8191] predictions, [8192] closs

  // ---- workspace carve ----
  char* p = (char*)d_ws;
  auto carve = [&](size_t bytes) -> char* {
    char* r = p; p += (bytes + 255) & ~(size_t)255; return r;
  };
  const size_t NODE_F = (size_t)NNODE*KD;
  float* ssb = (float*)carve((size_t)8*NNODE*4);
  float* ss0 = ssb,            *sd0 = ssb + NNODE;
  float* ss3 = ssb + 2*NNODE,  *sd3 = ssb + 5*NNODE;
  unsigned short* hb0 = (unsigned short*)carve(NODE_F*2);        // layer-1 h (shared)
  unsigned short* hb3 = (unsigned short*)carve(3*NODE_F*2);      // layer-2 h x3
  // time-multiplexed: CSR partials (6.4 MB) -> layer-1 agg bf16 out (6.4 MB)
  char* Creg = carve((size_t)8*HB*NNODE*4);
  int*   part = (int*)Creg;                       // part[3][HB][NNODE]
  int*   boff = (int*)Creg + (size_t)3*HB*NNODE;  // boff[3][HB][NNODE]
  unsigned short* etb = (unsigned short*)Creg;    // layer-1 agg out, bf16 [3*NNODE][KD]
  float* eoutAll = (float*)carve((size_t)(NS + NE)*KD*4);        // main-graph layer-2 out
  int* cnt_all = (int*)carve((size_t)3*NNODE*4);
  int* rp_all  = (int*)carve((size_t)3*RP*4);
  unsigned short* col_all = (unsigned short*)carve((size_t)3*NCSR*2);
  float* pWT = (float*)carve((size_t)3*KD*KD*4);
  float* pW1T = pWT, *pW2T = pWT + KD*KD, *pW3T = pWT + 2*KD*KD;
  float* rsp = (float*)carve((size_t)2*64*NS*4);   // rowsum partials
  float* csp = (float*)carve((size_t)2*64*NS*4);   // colsum partials
  float* dg_all = (float*)carve((size_t)2*NS*4);
  float* pbuf = (float*)carve(64*4);
  unsigned short* Z = (unsigned short*)carve((size_t)2*8192*KD*2);  // bf16 Z1|Z2

  // ---- CSR build (atomic-free, all stages parallel) + weight transpose ----
  k_hist<<<dim3(HB, 3), 256, 0, stream>>>(ep, part);
  k_sumpart<<<(3*NNODE + 255)/256, 256, 0, stream>>>(part, cnt_all);
  k_scan<<<3, 1024, 0, stream>>>(cnt_all, rp_all);
  k_boff<<<(3*NNODE + 255)/256, 256, 0, stream>>>(part, rp_all, boff);
  k_scatter<<<dim3(HB, 3), 256, 0, stream>>>(ep, boff, col_all);
  k_tr<<<dim3(4, 4, 3), dim3(32, 8), 0, stream>>>(pW1, pW2, pW3, pWT);

  // ---- GAT layer 1 (h shared across graphs; embedding gather fused; bf16 h) ----
  k_ngemm<3><<<NNODE/32, 256, 0, stream>>>(nullptr, W1, nullptr, nullptr, a1s, a1d,
                                           nullptr, hb0, ss0, sd0, NNODE,
                                           E_stu, E_exer, E_k, stu_ids, exer_ids, k_ids);
  k_agg<<<3*NNODE/4, 256, 0, stream>>>(rp_all, col_all, hb0, ss0, sd0, etb, nullptr, nullptr);

  // ---- GAT layer 2 (bf16 input) ----
  k_ngemm<0><<<3*NNODE/32, 256, 0, stream>>>(etb, W2, nullptr, nullptr, a2s, a2d,
                                             nullptr, hb3, ss3, sd3, 3*NNODE,
                                             nullptr, nullptr, nullptr, nullptr, nullptr, nullptr);
  k_agg<<<3*NNODE/4, 256, 0, stream>>>(rp_all, col_all, hb3, ss3, sd3, nullptr, eoutAll, Z);

  // ---- contrastive loss (bf16 MFMA sim, atomic-free epilogue) ----
  k_sim<<<dim3(32, 32, 2), 256, 0, stream>>>(Z, rsp, csp, dg_all);
  k_lred<<<dim3(16, 2), 256, 0, stream>>>(rsp, csp, dg_all, pbuf);
  k_lfin<<<1, 64, 0, stream>>>(pbuf, out);

  // ---- prediction head (fully fused, 16 rows/block -> 512 blocks) ----
  k_ngemm<4><<<BQ/16, 256, 0, stream>>>(nullptr, pW1T, pW2T, pW3T, pb3, kn_r,
                                        out, nullptr, nullptr, nullptr, BQ,
                                        eoutAll, nullptr, nullptr, stu_index, exer_index, nullptr);
}

// Round 11
// 334.234 us; speedup vs baseline: 1.1895x; 1.0018x over previous
//
#include <hip/hip_runtime.h>
#include <hip/hip_bf16.h>
#include <math.h>

#define KD 128
#define NS 4096
#define NE 4096
#define NK 128
#define NNODE (NS + NE + NK)      // 8320
#define ESE 131072
#define EEK 16384
#define NCSR (2*ESE + 2*EEK)      // 294912
#define BQ 8192
#define RP (NNODE + 1)
#define HB 32                     // CSR-build blocks per graph

typedef __attribute__((ext_vector_type(8))) short short8;   // 8 bf16 (4 VGPRs)
typedef __attribute__((ext_vector_type(4))) float float4_;  // 4 fp32 acc

__device__ __forceinline__ float lrelu_(float x){ return x >= 0.f ? x : 0.2f*x; }
__device__ __forceinline__ float elu_(float x){ return x > 0.f ? x : __expf(x) - 1.f; }
__device__ __forceinline__ float sigm_(float x){ return 1.f/(1.f + __expf(-x)); }
__device__ __forceinline__ float bf2f_(unsigned short u){
  union { unsigned int i; float f; } v; v.i = ((unsigned int)u) << 16; return v.f;
}
__device__ __forceinline__ unsigned short f2b_(float x){
  __hip_bfloat16 b = __float2bfloat16(x); return *(unsigned short*)&b;
}

struct EdgePtrs { const int* s_src[3]; const int* s_dst[3]; const int* e_src[3]; const int* e_dst[3]; };

// ---------- CSR build: LDS histogram -> per-block partial counts (no global atomics) ----------
__global__ __launch_bounds__(256)
void k_hist(EdgePtrs ep, int* __restrict__ part) {
  __shared__ int hcnt[NNODE];     // 33 KB
  int g = blockIdx.y, b = blockIdx.x, t = threadIdx.x;
  for (int i = t; i < NNODE; i += 256) hcnt[i] = 0;
  __syncthreads();
  const int* ss_ = ep.s_src[g]; const int* sd_ = ep.s_dst[g];
  const int* es_ = ep.e_src[g]; const int* ed_ = ep.e_dst[g];
  int se0 = b*(ESE/HB);
  for (int i = se0 + t; i < se0 + ESE/HB; i += 256) {
    atomicAdd(&hcnt[ss_[i]], 1);
    atomicAdd(&hcnt[NS + sd_[i]], 1);
  }
  int ek0 = b*(EEK/HB);
  for (int i = ek0 + t; i < ek0 + EEK/HB; i += 256) {
    atomicAdd(&hcnt[NS + es_[i]], 1);
    atomicAdd(&hcnt[NS + NE + ed_[i]], 1);
  }
  __syncthreads();
  int* pp = part + ((size_t)g*HB + b)*NNODE;
  for (int i = t; i < NNODE; i += 256) pp[i] = hcnt[i];
}

// thread-per-node partial-sum: cnt[g][n] = sum_b part[g][b][n]  (coalesced over n)
__global__ void k_sumpart(const int* __restrict__ part, int* __restrict__ cnt_all) {
  int idx = blockIdx.x*256 + threadIdx.x;
  if (idx >= 3*NNODE) return;
  int g = idx / NNODE, n = idx - g*NNODE;
  const int* pg = part + (size_t)g*HB*NNODE + n;
  int s = 0;
  #pragma unroll
  for (int b = 0; b < HB; b++) s += pg[(size_t)b*NNODE];
  cnt_all[idx] = s;
}

// per-graph single-block scan of cnt -> row_ptr (lightweight: 9 reads/thread)
__global__ void k_scan(const int* __restrict__ cnt_all, int* __restrict__ rp_all) {
  __shared__ int sums[1024];
  const int CH = (NNODE + 1023) / 1024;    // 9
  int g = blockIdx.x, t = threadIdx.x;
  const int* cnt = cnt_all + g*NNODE;
  int* row_ptr = rp_all + g*RP;
  int base = t*CH;
  int local[CH];
  int s = 0;
  for (int j = 0; j < CH; j++) {
    int v = (base + j < NNODE) ? cnt[base + j] : 0;
    local[j] = s; s += v;
  }
  sums[t] = s; __syncthreads();
  for (int off = 1; off < 1024; off <<= 1) {
    int v = (t >= off) ? sums[t - off] : 0;
    __syncthreads();
    sums[t] += v;
    __syncthreads();
  }
  int excl = (t == 0) ? 0 : sums[t - 1];
  for (int j = 0; j < CH; j++)
    if (base + j < NNODE) row_ptr[base + j] = excl + local[j];
  if (t == 1023) row_ptr[NNODE] = sums[1023];
}

// thread-per-node: emit per-block cursors boff[g][b][n] (coalesced over n)
__global__ void k_boff(const int* __restrict__ part, const int* __restrict__ rp_all,
                       int* __restrict__ boff) {
  int idx = blockIdx.x*256 + threadIdx.x;
  if (idx >= 3*NNODE) return;
  int g = idx / NNODE, n = idx - g*NNODE;
  const int* pg = part + (size_t)g*HB*NNODE + n;
  int* bg = boff + (size_t)g*HB*NNODE + n;
  int acc = rp_all[g*RP + n];
  #pragma unroll
  for (int b = 0; b < HB; b++) {
    bg[(size_t)b*NNODE] = acc;
    acc += pg[(size_t)b*NNODE];
  }
}

// scatter via LDS cursors initialized from boff (no global atomics); col stored ushort
__global__ __launch_bounds__(256)
void k_scatter(EdgePtrs ep, const int* __restrict__ boff, unsigned short* __restrict__ col_all) {
  __shared__ int cur[NNODE];      // 33 KB live cursors
  int g = blockIdx.y, b = blockIdx.x, t = threadIdx.x;
  const int* bg = boff + ((size_t)g*HB + b)*NNODE;
  for (int i = t; i < NNODE; i += 256) cur[i] = bg[i];
  __syncthreads();
  const int* ss_ = ep.s_src[g]; const int* sd_ = ep.s_dst[g];
  const int* es_ = ep.e_src[g]; const int* ed_ = ep.e_dst[g];
  unsigned short* col = col_all + (size_t)g*NCSR;
  int se0 = b*(ESE/HB);
  for (int i = se0 + t; i < se0 + ESE/HB; i += 256) {
    int s = ss_[i], d = NS + sd_[i];
    col[atomicAdd(&cur[s], 1)] = (unsigned short)d;
    col[atomicAdd(&cur[d], 1)] = (unsigned short)s;
  }
  int ek0 = b*(EEK/HB);
  for (int i = ek0 + t; i < ek0 + EEK/HB; i += 256) {
    int s = NS + es_[i], d = NS + NE + ed_[i];
    col[atomicAdd(&cur[s], 1)] = (unsigned short)d;
    col[atomicAdd(&cur[d], 1)] = (unsigned short)s;
  }
}

// ---------- transpose the 3 head weight matrices ----------
__global__ void k_tr(const float* __restrict__ pW1, const float* __restrict__ pW2,
                     const float* __restrict__ pW3, float* __restrict__ T) {
  __shared__ float tile[32][33];
  int m = blockIdx.z;
  const float* src = m == 0 ? pW1 : (m == 1 ? pW2 : pW3);
  float* dst = T + m*KD*KD;
  int bx = blockIdx.x*32, by = blockIdx.y*32;
  int tx = threadIdx.x, ty = threadIdx.y;   // block (32,8)
  for (int j = 0; j < 32; j += 8)
    tile[ty + j][tx] = src[(by + ty + j)*KD + bx + tx];
  __syncthreads();
  for (int j = 0; j < 32; j += 8)
    dst[(bx + ty + j)*KD + by + tx] = tile[tx][ty + j];
}

// ---------- register-blocked node GEMM ----------
// MODE 0: hb = bf16(inb@Wa) + fused ss/sd (v1=a_s, v2=a_d); bf16 input; 32 rows/block
// MODE 3: same epilogue, stages fp32 rows gathered from embedding tables; 32 rows/block
// MODE 4: fused head, 16 rows/block: bs=g1[i1], be=g1[NS+i2]; P=sigm(bs@Wa), D=sigm(be@Wb),
//         o=sigm((P-D)@Wc + v1); out[row]=sum(o*v2)/sum(v2). Block 0 wave 0 also
//         finalizes closs from pbuf (passed via sd) -> out[BQ].
template<int MODE>
__global__ __launch_bounds__(256)
void k_ngemm(const unsigned short* __restrict__ inb,
             const float* __restrict__ Wa, const float* __restrict__ Wb,
             const float* __restrict__ Wc,
             const float* __restrict__ v1, const float* __restrict__ v2,
             float* __restrict__ out, unsigned short* __restrict__ hb,
             float* __restrict__ ss, float* __restrict__ sd,
             int nrows,
             const float* __restrict__ g1, const float* __restrict__ g2,
             const float* __restrict__ g3,
             const int* __restrict__ i1, const int* __restrict__ i2,
             const int* __restrict__ i3) {
  constexpr int ROWS = (MODE == 4) ? 16 : 32;   // rows per block
  constexpr int RPW  = ROWS/4;                  // rows per wave
  __shared__ float ers[ROWS][KD];
  __shared__ float xs[(MODE == 4) ? ROWS : 1][KD];
  int t = threadIdx.x;
  int row0 = blockIdx.x * ROWS;
  int w = t >> 6, c = t & 63;

  // ---- stage pass 1 ----
  for (int i = t; i < ROWS*KD; i += 256) {
    int r = i >> 7, k = i & 127;
    int gr = row0 + r;
    float val;
    if (MODE == 3) {
      const float* srow;
      if (gr < NS)           srow = g1 + (size_t)i1[gr]*KD;
      else if (gr < NS + NE) srow = g2 + (size_t)i2[gr - NS]*KD;
      else                   srow = g3 + (size_t)i3[gr - NS - NE]*KD;
      val = srow[k];
    } else if (MODE == 4) {
      val = g1[(size_t)i1[gr]*KD + k];
    } else {
      val = (gr < nrows) ? bf2f_(inb[(size_t)gr*KD + k]) : 0.f;
    }
    ers[r][k] = val;
  }
  __syncthreads();

  float acc0[RPW], acc1[RPW];
  #pragma unroll
  for (int r = 0; r < RPW; r++) { acc0[r] = 0.f; acc1[r] = 0.f; }
  #pragma unroll 2
  for (int kc = 0; kc < KD; kc += 4) {
    float wa[4], wb[4];
    #pragma unroll
    for (int j = 0; j < 4; j++) {
      wa[j] = Wa[(kc + j)*KD + c];
      wb[j] = Wa[(kc + j)*KD + c + 64];
    }
    #pragma unroll
    for (int r = 0; r < RPW; r++) {
      float4 e = *(const float4*)&ers[w*RPW + r][kc];   // wave-uniform broadcast read
      acc0[r] += e.x*wa[0] + e.y*wa[1] + e.z*wa[2] + e.w*wa[3];
      acc1[r] += e.x*wb[0] + e.y*wb[1] + e.z*wb[2] + e.w*wb[3];
    }
  }

  if (MODE == 0 || MODE == 3) {
    float as1 = v1[c], as2 = v1[c + 64], ad1 = v2[c], ad2 = v2[c + 64];
    #pragma unroll
    for (int r = 0; r < RPW; r++) {
      int gr = row0 + w*RPW + r;
      if (gr < nrows) {
        hb[(size_t)gr*KD + c]      = f2b_(acc0[r]);
        hb[(size_t)gr*KD + c + 64] = f2b_(acc1[r]);
      }
      float s = acc0[r]*as1 + acc1[r]*as2;
      float d = acc0[r]*ad1 + acc1[r]*ad2;
      #pragma unroll
      for (int off = 32; off; off >>= 1) { s += __shfl_xor(s, off); d += __shfl_xor(d, off); }
      if (c == 0 && gr < nrows) { ss[gr] = s; sd[gr] = d; }
    }
    return;
  }

  if (MODE == 4) {
    #pragma unroll
    for (int r = 0; r < RPW; r++) {
      xs[w*RPW + r][c]      = sigm_(acc0[r]);
      xs[w*RPW + r][c + 64] = sigm_(acc1[r]);
    }
    __syncthreads();   // all waves done reading ers (GEMM1)
    for (int i = t; i < ROWS*KD; i += 256) {
      int r = i >> 7, k = i & 127;
      int gr = row0 + r;
      ers[r][k] = g1[(size_t)(NS + i2[gr])*KD + k];
    }
    __syncthreads();
    #pragma unroll
    for (int r = 0; r < RPW; r++) { acc0[r] = 0.f; acc1[r] = 0.f; }
    #pragma unroll 2
    for (int kc = 0; kc < KD; kc += 4) {
      float wa[4], wb[4];
      #pragma unroll
      for (int j = 0; j < 4; j++) {
        wa[j] = Wb[(kc + j)*KD + c];
        wb[j] = Wb[(kc + j)*KD + c + 64];
      }
      #pragma unroll
      for (int r = 0; r < RPW; r++) {
        float4 e = *(const float4*)&ers[w*RPW + r][kc];
        acc0[r] += e.x*wa[0] + e.y*wa[1] + e.z*wa[2] + e.w*wa[3];
        acc1[r] += e.x*wb[0] + e.y*wb[1] + e.z*wb[2] + e.w*wb[3];
      }
    }
    #pragma unroll
    for (int r = 0; r < RPW; r++) {     // xs rows are wave-private
      xs[w*RPW + r][c]      -= sigm_(acc0[r]);
      xs[w*RPW + r][c + 64] -= sigm_(acc1[r]);
    }
    #pragma unroll
    for (int r = 0; r < RPW; r++) { acc0[r] = 0.f; acc1[r] = 0.f; }
    #pragma unroll 2
    for (int kc = 0; kc < KD; kc += 4) {
      float wa[4], wb[4];
      #pragma unroll
      for (int j = 0; j < 4; j++) {
        wa[j] = Wc[(kc + j)*KD + c];
        wb[j] = Wc[(kc + j)*KD + c + 64];
      }
      #pragma unroll
      for (int r = 0; r < RPW; r++) {
        float4 e = *(const float4*)&xs[w*RPW + r][kc];
        acc0[r] += e.x*wa[0] + e.y*wa[1] + e.z*wa[2] + e.w*wa[3];
        acc1[r] += e.x*wb[0] + e.y*wb[1] + e.z*wb[2] + e.w*wb[3];
      }
    }
    float b1 = v1[c], b2 = v1[c + 64];
    #pragma unroll
    for (int r = 0; r < RPW; r++) {
      int gr = row0 + w*RPW + r;
      float kr1 = v2[(size_t)gr*KD + c], kr2 = v2[(size_t)gr*KD + c + 64];
      float o1 = sigm_(acc0[r] + b1), o2 = sigm_(acc1[r] + b2);
      float num = o1*kr1 + o2*kr2, den = kr1 + kr2;
      #pragma unroll
      for (int off = 32; off; off >>= 1) { num += __shfl_xor(num, off); den += __shfl_xor(den, off); }
      if (c == 0) out[gr] = num/den;
    }
    // fold-in: finalize closs from pbuf (sd) on block 0, wave 0
    if (blockIdx.x == 0 && w == 0) {
      int lane = t & 63;
      float v = (lane < 32) ? sd[lane] : 0.f;
      #pragma unroll
      for (int off = 32; off; off >>= 1) v += __shfl_xor(v, off);
      if (lane == 0) out[BQ] = 0.1f*v/(float)NS;
    }
  }
}

// ---------- segment-softmax aggregation ----------
// gsel < 0 : layer 1, 3 graphs batched (shared bf16 h table), bf16 out rows.
// gsel >= 0: layer 2 for graph gsel only (per-graph launch keeps the 2.1 MB
//            gather slice L2-resident): g0 -> fp32 out, g1/g2 -> normalized bf16 Z.
// 2-deep MLP: each 16-lane subgroup processes 2 edges per j-iter (2 row loads
// in flight), VGPR stays ~32 (R9's 16-deep variant hit 88 VGPR and regressed).
__global__ __launch_bounds__(256)
void k_agg(const int* __restrict__ rp_all, const unsigned short* __restrict__ col_all,
           const unsigned short* __restrict__ hb_base, const float* __restrict__ ss,
           const float* __restrict__ sd, unsigned short* __restrict__ outb,
           float* __restrict__ out, unsigned short* __restrict__ Zo, int gsel) {
  int wv = blockIdx.x*4 + (threadIdx.x >> 6);
  int lane = threadIdx.x & 63;
  int g, node;
  if (gsel < 0) {
    if (wv >= 3*NNODE) return;
    g = wv / NNODE; node = wv - g*NNODE;
  } else {
    g = gsel; node = wv;
    if (node >= NS + NE) return;
  }
  const int* rp = rp_all + g*RP;
  const unsigned short* cl = col_all + (size_t)g*NCSR;
  const unsigned short* hgb = (gsel < 0) ? hb_base : hb_base + (size_t)g*NNODE*KD;
  const float* ssg = (gsel < 0) ? ss : ss + g*NNODE;
  const float* sdg = (gsel < 0) ? sd : sd + g*NNODE;
  int e0 = rp[node], e1 = rp[node + 1];
  float sdv = sdg[node];
  int sub = lane >> 4;       // edge subgroup 0..3
  int fl  = lane & 15;       // feature lane: features fl*8 .. fl*8+7
  float l = 0.f;
  float A[8] = {0,0,0,0,0,0,0,0};
  for (int base = e0; base < e1; base += 64) {
    int e = base + lane;
    float p = 0.f; int o = 0;
    if (e < e1) { o = cl[e]; p = __expf(lrelu_(ssg[o] + sdv)); }
    l += p;
    int cnt = min(64, e1 - base);
    #pragma unroll 2
    for (int j = 0; j*8 < cnt; j++) {
      int idx0 = j*8 + sub;        // this subgroup's two edges this iter
      int idx1 = idx0 + 4;
      float p0 = __shfl(p, idx0), p1 = __shfl(p, idx1);
      int   o0 = __shfl(o, idx0),  o1 = __shfl(o, idx1);
      bool a0 = idx0 < cnt, a1 = idx1 < cnt;
      short8 mv0, mv1;
      if (a0) mv0 = *(const short8*)&hgb[(size_t)o0*KD + fl*8];
      if (a1) mv1 = *(const short8*)&hgb[(size_t)o1*KD + fl*8];
      if (a0) {
        #pragma unroll
        for (int q = 0; q < 8; q++) A[q] += p0 * bf2f_((unsigned short)mv0[q]);
      }
      if (a1) {
        #pragma unroll
        for (int q = 0; q < 8; q++) A[q] += p1 * bf2f_((unsigned short)mv1[q]);
      }
    }
  }
  #pragma unroll
  for (int off = 32; off; off >>= 1) l += __shfl_xor(l, off);
  #pragma unroll
  for (int q = 0; q < 8; q++) {
    A[q] += __shfl_xor(A[q], 16);
    A[q] += __shfl_xor(A[q], 32);
  }
  float inv = 1.f/(l + 1e-16f);
  float av[8];
  #pragma unroll
  for (int q = 0; q < 8; q++) av[q] = elu_(A[q]*inv);
  if (gsel < 0) {
    if (sub == 0) {
      short8 sv;
      #pragma unroll
      for (int q = 0; q < 8; q++) sv[q] = (short)f2b_(av[q]);
      *(short8*)&outb[(size_t)wv*KD + fl*8] = sv;
    }
    return;
  }
  if (g == 0) {
    if (sub == 0) {
      float* orow = &out[(size_t)node*KD + fl*8];
      *(float4*)orow       = make_float4(av[0], av[1], av[2], av[3]);
      *(float4*)(orow + 4) = make_float4(av[4], av[5], av[6], av[7]);
    }
  } else {
    float nrm = av[0]*av[0] + av[1]*av[1] + av[2]*av[2] + av[3]*av[3]
              + av[4]*av[4] + av[5]*av[5] + av[6]*av[6] + av[7]*av[7];
    #pragma unroll
    for (int off = 1; off <= 8; off <<= 1) nrm += __shfl_xor(nrm, off);
    float invn = 1.f/(sqrtf(nrm) + 1e-12f);
    if (sub == 0) {
      short8 sv;
      #pragma unroll
      for (int q = 0; q < 8; q++) sv[q] = (short)f2b_(av[q]*invn);
      *(short8*)&Zo[((size_t)(g - 1)*8192 + node)*KD + fl*8] = sv;
    }
  }
}

// ---------- bf16 MFMA similarity GEMM, atomic-free partial-sum epilogue ----------
// grid (32,32,2). rsp/csp: [2][64][NS] partials, unique writer per element.
__global__ __launch_bounds__(256)
void k_sim(const unsigned short* __restrict__ Z, float* __restrict__ rsp,
           float* __restrict__ csp, float* __restrict__ dg_all) {
  __shared__ unsigned short As[128*KD];   // 32 KB, row r: 16 groups of 8, group g at (g ^ (r&15))
  __shared__ unsigned short Bs[128*KD];   // 32 KB
  int z = blockIdx.z;
  int t = threadIdx.x;
  const unsigned short* Arow = Z + ((size_t)z*NS + (size_t)blockIdx.x*128)*KD;
  const unsigned short* Brow = Z + ((size_t)8192 + (size_t)z*NS + (size_t)blockIdx.y*128)*KD;
  #pragma unroll
  for (int j = 0; j < 8; j++) {
    int G = t + j*256;                     // linear 16B-group id, 0..2047
    int r = G >> 4, g = G & 15;
    int sw = g ^ (r & 15);
    *(float4*)&As[(r*16 + sw)*8] = *(const float4*)&Arow[(size_t)G*8];
    *(float4*)&Bs[(r*16 + sw)*8] = *(const float4*)&Brow[(size_t)G*8];
  }
  __syncthreads();
  int w = t >> 6, lane = t & 63;
  int rw = (w >> 1)*64, cw = (w & 1)*64;
  int m15 = lane & 15, quad = lane >> 4;
  float4_ acc[4][4] = {};
  #pragma unroll
  for (int kq = 0; kq < 4; kq++) {
    short8 a[4], b[4];
    int g = kq*4 + quad;
    #pragma unroll
    for (int mi = 0; mi < 4; mi++) {
      int r = rw + mi*16 + m15;
      a[mi] = *(const short8*)&As[(r*16 + (g ^ (r & 15)))*8];
    }
    #pragma unroll
    for (int ni = 0; ni < 4; ni++) {
      int r = cw + ni*16 + m15;
      b[ni] = *(const short8*)&Bs[(r*16 + (g ^ (r & 15)))*8];
    }
    #pragma unroll
    for (int mi = 0; mi < 4; mi++)
      #pragma unroll
      for (int ni = 0; ni < 4; ni++)
        acc[mi][ni] = __builtin_amdgcn_mfma_f32_16x16x32_bf16(a[mi], b[ni], acc[mi][ni], 0, 0, 0);
  }
  int i0 = blockIdx.x*128, j0 = blockIdx.y*128;
  float* diag = dg_all + z*NS;
  float* rrow = rsp + ((size_t)z*64 + blockIdx.y*2 + (w & 1))*NS;
  float* crow = csp + ((size_t)z*64 + blockIdx.x*2 + (w >> 1))*NS;
  float cs[4] = {0,0,0,0};
  #pragma unroll
  for (int mi = 0; mi < 4; mi++) {
    float rs[4] = {0,0,0,0};
    #pragma unroll
    for (int ni = 0; ni < 4; ni++) {
      #pragma unroll
      for (int reg = 0; reg < 4; reg++) {
        float sim2 = acc[mi][ni][reg]*2.0f;
        int gi = i0 + rw + mi*16 + quad*4 + reg;     // C/D: row=(lane>>4)*4+reg
        int gj = j0 + cw + ni*16 + m15;              //      col=lane&15
        if (gi == gj) diag[gi] = sim2;
        float e = __expf(sim2);
        rs[reg] += e; cs[ni] += e;
      }
    }
    #pragma unroll
    for (int reg = 0; reg < 4; reg++) {
      float v = rs[reg];
      v += __shfl_xor(v, 1); v += __shfl_xor(v, 2);
      v += __shfl_xor(v, 4); v += __shfl_xor(v, 8);
      if (m15 == 0) rrow[i0 + rw + mi*16 + quad*4 + reg] = v;
    }
  }
  #pragma unroll
  for (int ni = 0; ni < 4; ni++) {
    float v = cs[ni];
    v += __shfl_xor(v, 16); v += __shfl_xor(v, 32);
    if (quad == 0) crow[j0 + cw + ni*16 + m15] = v;
  }
}

// reduce partials -> per-block loss partial (grid (16,2))
__global__ void k_lred(const float* __restrict__ rsp, const float* __restrict__ csp,
                       const float* __restrict__ dg_all, float* __restrict__ pbuf) {
  __shared__ float red[256];
  int z = blockIdx.y;
  int i = blockIdx.x*256 + threadIdx.x;
  float rs = 0.f, cs = 0.f;
  for (int s = 0; s < 64; s++) {
    rs += rsp[((size_t)z*64 + s)*NS + i];
    cs += csp[((size_t)z*64 + s)*NS + i];
  }
  float v = logf(rs) + logf(cs) - 2.f*dg_all[z*NS + i];
  red[threadIdx.x] = v; __syncthreads();
  for (int off = 128; off; off >>= 1) {
    if (threadIdx.x < off) red[threadIdx.x] += red[threadIdx.x + off];
    __syncthreads();
  }
  if (threadIdx.x == 0) pbuf[z*16 + blockIdx.x] = red[0];
}

extern "C" void kernel_launch(void* const* d_in, const int* in_sizes, int n_in,
                              void* d_out, int out_size, void* d_ws, size_t ws_size,
                              hipStream_t stream) {
  const float* E_stu  = (const float*)d_in[0];
  const float* E_exer = (const float*)d_in[1];
  const float* E_k    = (const float*)d_in[2];
  const float* W1  = (const float*)d_in[3];
  const float* a1s = (const float*)d_in[4];
  const float* a1d = (const float*)d_in[5];
  const float* W2  = (const float*)d_in[6];
  const float* a2s = (const float*)d_in[7];
  const float* a2d = (const float*)d_in[8];
  const float* pW1 = (const float*)d_in[9];
  const float* pW2 = (const float*)d_in[10];
  const float* pW3 = (const float*)d_in[11];
  const float* pb3 = (const float*)d_in[12];
  const float* kn_r = (const float*)d_in[13];
  const int* stu_ids  = (const int*)d_in[14];
  const int* exer_ids = (const int*)d_in[15];
  const int* k_ids    = (const int*)d_in[16];
  EdgePtrs ep;
  for (int g = 0; g < 3; g++) {
    ep.s_src[g] = (const int*)d_in[17 + g*4];
    ep.s_dst[g] = (const int*)d_in[18 + g*4];
    ep.e_src[g] = (const int*)d_in[19 + g*4];
    ep.e_dst[g] = (const int*)d_in[20 + g*4];
  }
  const int* stu_index  = (const int*)d_in[29];
  const int* exer_index = (const int*)d_in[30];
  float* out = (float*)d_out;   // [0..8191] predictions, [8192] closs

  // ---- workspace carve ----
  char* p = (char*)d_ws;
  auto carve = [&](size_t bytes) -> char* {
    char* r = p; p += (bytes + 255) & ~(size_t)255; return r;
  };
  const size_t NODE_F = (size_t)NNODE*KD;
  float* ssb = (float*)carve((size_t)8*NNODE*4);
  float* ss0 = ssb,            *sd0 = ssb + NNODE;
  float* ss3 = ssb + 2*NNODE,  *sd3 = ssb + 5*NNODE;
  unsigned short* hb0 = (unsigned short*)carve(NODE_F*2);        // layer-1 h (shared)
  unsigned short* hb3 = (unsigned short*)carve(3*NODE_F*2);      // layer-2 h x3
  // time-multiplexed: CSR partials (6.4 MB) -> layer-1 agg bf16 out (6.4 MB)
  char* Creg = carve((size_t)8*HB*NNODE*4);
  int*   part = (int*)Creg;                       // part[3][HB][NNODE]
  int*   boff = (int*)Creg + (size_t)3*HB*NNODE;  // boff[3][HB][NNODE]
  unsigned short* etb = (unsigned short*)Creg;    // layer-1 agg out, bf16 [3*NNODE][KD]
  float* eoutAll = (float*)carve((size_t)(NS + NE)*KD*4);        // main-graph layer-2 out
  int* cnt_all = (int*)carve((size_t)3*NNODE*4);
  int* rp_all  = (int*)carve((size_t)3*RP*4);
  unsigned short* col_all = (unsigned short*)carve((size_t)3*NCSR*2);
  float* pWT = (float*)carve((size_t)3*KD*KD*4);
  float* pW1T = pWT, *pW2T = pWT + KD*KD, *pW3T = pWT + 2*KD*KD;
  float* rsp = (float*)carve((size_t)2*64*NS*4);   // rowsum partials
  float* csp = (float*)carve((size_t)2*64*NS*4);   // colsum partials
  float* dg_all = (float*)carve((size_t)2*NS*4);
  float* pbuf = (float*)carve(64*4);
  unsigned short* Z = (unsigned short*)carve((size_t)2*8192*KD*2);  // bf16 Z1|Z2

  // ---- CSR build (atomic-free, all stages parallel) + weight transpose ----
  k_hist<<<dim3(HB, 3), 256, 0, stream>>>(ep, part);
  k_sumpart<<<(3*NNODE + 255)/256, 256, 0, stream>>>(part, cnt_all);
  k_scan<<<3, 1024, 0, stream>>>(cnt_all, rp_all);
  k_boff<<<(3*NNODE + 255)/256, 256, 0, stream>>>(part, rp_all, boff);
  k_scatter<<<dim3(HB, 3), 256, 0, stream>>>(ep, boff, col_all);
  k_tr<<<dim3(4, 4, 3), dim3(32, 8), 0, stream>>>(pW1, pW2, pW3, pWT);

  // ---- GAT layer 1 (h shared across graphs; embedding gather fused; bf16 h) ----
  k_ngemm<3><<<NNODE/32, 256, 0, stream>>>(nullptr, W1, nullptr, nullptr, a1s, a1d,
                                           nullptr, hb0, ss0, sd0, NNODE,
                                           E_stu, E_exer, E_k, stu_ids, exer_ids, k_ids);
  k_agg<<<3*NNODE/4, 256, 0, stream>>>(rp_all, col_all, hb0, ss0, sd0, etb,
                                       nullptr, nullptr, -1);

  // ---- GAT layer 2 (bf16 input; per-graph agg launches for L2 residency) ----
  k_ngemm<0><<<3*NNODE/32, 256, 0, stream>>>(etb, W2, nullptr, nullptr, a2s, a2d,
                                             nullptr, hb3, ss3, sd3, 3*NNODE,
                                             nullptr, nullptr, nullptr, nullptr, nullptr, nullptr);
  for (int g = 0; g < 3; g++)
    k_agg<<<(NS + NE)/4, 256, 0, stream>>>(rp_all, col_all, hb3, ss3, sd3, nullptr,
                                           eoutAll, Z, g);

  // ---- contrastive loss (bf16 MFMA sim, atomic-free epilogue) ----
  k_sim<<<dim3(32, 32, 2), 256, 0, stream>>>(Z, rsp, csp, dg_all);
  k_lred<<<dim3(16, 2), 256, 0, stream>>>(rsp, csp, dg_all, pbuf);

  // ---- prediction head (fused; block 0 also finalizes closs from pbuf) ----
  k_ngemm<4><<<BQ/16, 256, 0, stream>>>(nullptr, pW1T, pW2T, pW3T, pb3, kn_r,
                                        out, nullptr, nullptr, pbuf, BQ,
                                        eoutAll, nullptr, nullptr, stu_index, exer_index, nullptr);
}

// Round 12
// 334.191 us; speedup vs baseline: 1.1896x; 1.0001x over previous
//
#include <hip/hip_runtime.h>
#include <hip/hip_bf16.h>
#include <math.h>

#define KD 128
#define NS 4096
#define NE 4096
#define NK 128
#define NNODE (NS + NE + NK)      // 8320
#define ESE 131072
#define EEK 16384
#define NCSR (2*ESE + 2*EEK)      // 294912
#define BQ 8192
#define RP (NNODE + 1)
#define HB 32                     // CSR-build blocks per graph

typedef __attribute__((ext_vector_type(8))) short short8;   // 8 bf16 (4 VGPRs)
typedef __attribute__((ext_vector_type(4))) float float4_;  // 4 fp32 acc

__device__ __forceinline__ float lrelu_(float x){ return x >= 0.f ? x : 0.2f*x; }
__device__ __forceinline__ float elu_(float x){ return x > 0.f ? x : __expf(x) - 1.f; }
__device__ __forceinline__ float sigm_(float x){ return 1.f/(1.f + __expf(-x)); }
__device__ __forceinline__ float bf2f_(unsigned short u){
  union { unsigned int i; float f; } v; v.i = ((unsigned int)u) << 16; return v.f;
}
__device__ __forceinline__ unsigned short f2b_(float x){
  __hip_bfloat16 b = __float2bfloat16(x); return *(unsigned short*)&b;
}

struct EdgePtrs { const int* s_src[3]; const int* s_dst[3]; const int* e_src[3]; const int* e_dst[3]; };

// ---------- CSR build: LDS histogram -> per-block partial counts (no global atomics) ----------
__global__ __launch_bounds__(256)
void k_hist(EdgePtrs ep, int* __restrict__ part) {
  __shared__ int hcnt[NNODE];     // 33 KB
  int g = blockIdx.y, b = blockIdx.x, t = threadIdx.x;
  for (int i = t; i < NNODE; i += 256) hcnt[i] = 0;
  __syncthreads();
  const int* ss_ = ep.s_src[g]; const int* sd_ = ep.s_dst[g];
  const int* es_ = ep.e_src[g]; const int* ed_ = ep.e_dst[g];
  int se0 = b*(ESE/HB);
  for (int i = se0 + t; i < se0 + ESE/HB; i += 256) {
    atomicAdd(&hcnt[ss_[i]], 1);
    atomicAdd(&hcnt[NS + sd_[i]], 1);
  }
  int ek0 = b*(EEK/HB);
  for (int i = ek0 + t; i < ek0 + EEK/HB; i += 256) {
    atomicAdd(&hcnt[NS + es_[i]], 1);
    atomicAdd(&hcnt[NS + NE + ed_[i]], 1);
  }
  __syncthreads();
  int* pp = part + ((size_t)g*HB + b)*NNODE;
  for (int i = t; i < NNODE; i += 256) pp[i] = hcnt[i];
}

// thread-per-node partial-sum: cnt[g][n] = sum_b part[g][b][n]  (coalesced over n)
__global__ void k_sumpart(const int* __restrict__ part, int* __restrict__ cnt_all) {
  int idx = blockIdx.x*256 + threadIdx.x;
  if (idx >= 3*NNODE) return;
  int g = idx / NNODE, n = idx - g*NNODE;
  const int* pg = part + (size_t)g*HB*NNODE + n;
  int s = 0;
  #pragma unroll
  for (int b = 0; b < HB; b++) s += pg[(size_t)b*NNODE];
  cnt_all[idx] = s;
}

// per-graph single-block scan of cnt -> row_ptr (lightweight: 9 reads/thread)
__global__ void k_scan(const int* __restrict__ cnt_all, int* __restrict__ rp_all) {
  __shared__ int sums[1024];
  const int CH = (NNODE + 1023) / 1024;    // 9
  int g = blockIdx.x, t = threadIdx.x;
  const int* cnt = cnt_all + g*NNODE;
  int* row_ptr = rp_all + g*RP;
  int base = t*CH;
  int local[CH];
  int s = 0;
  for (int j = 0; j < CH; j++) {
    int v = (base + j < NNODE) ? cnt[base + j] : 0;
    local[j] = s; s += v;
  }
  sums[t] = s; __syncthreads();
  for (int off = 1; off < 1024; off <<= 1) {
    int v = (t >= off) ? sums[t - off] : 0;
    __syncthreads();
    sums[t] += v;
    __syncthreads();
  }
  int excl = (t == 0) ? 0 : sums[t - 1];
  for (int j = 0; j < CH; j++)
    if (base + j < NNODE) row_ptr[base + j] = excl + local[j];
  if (t == 1023) row_ptr[NNODE] = sums[1023];
}

// thread-per-node: emit per-block cursors boff[g][b][n] (coalesced over n)
__global__ void k_boff(const int* __restrict__ part, const int* __restrict__ rp_all,
                       int* __restrict__ boff) {
  int idx = blockIdx.x*256 + threadIdx.x;
  if (idx >= 3*NNODE) return;
  int g = idx / NNODE, n = idx - g*NNODE;
  const int* pg = part + (size_t)g*HB*NNODE + n;
  int* bg = boff + (size_t)g*HB*NNODE + n;
  int acc = rp_all[g*RP + n];
  #pragma unroll
  for (int b = 0; b < HB; b++) {
    bg[(size_t)b*NNODE] = acc;
    acc += pg[(size_t)b*NNODE];
  }
}

// scatter via LDS cursors initialized from boff (no global atomics); col stored ushort
__global__ __launch_bounds__(256)
void k_scatter(EdgePtrs ep, const int* __restrict__ boff, unsigned short* __restrict__ col_all) {
  __shared__ int cur[NNODE];      // 33 KB live cursors
  int g = blockIdx.y, b = blockIdx.x, t = threadIdx.x;
  const int* bg = boff + ((size_t)g*HB + b)*NNODE;
  for (int i = t; i < NNODE; i += 256) cur[i] = bg[i];
  __syncthreads();
  const int* ss_ = ep.s_src[g]; const int* sd_ = ep.s_dst[g];
  const int* es_ = ep.e_src[g]; const int* ed_ = ep.e_dst[g];
  unsigned short* col = col_all + (size_t)g*NCSR;
  int se0 = b*(ESE/HB);
  for (int i = se0 + t; i < se0 + ESE/HB; i += 256) {
    int s = ss_[i], d = NS + sd_[i];
    col[atomicAdd(&cur[s], 1)] = (unsigned short)d;
    col[atomicAdd(&cur[d], 1)] = (unsigned short)s;
  }
  int ek0 = b*(EEK/HB);
  for (int i = ek0 + t; i < ek0 + EEK/HB; i += 256) {
    int s = NS + es_[i], d = NS + NE + ed_[i];
    col[atomicAdd(&cur[s], 1)] = (unsigned short)d;
    col[atomicAdd(&cur[d], 1)] = (unsigned short)s;
  }
}

// ---------- transpose the 3 head weight matrices ----------
__global__ void k_tr(const float* __restrict__ pW1, const float* __restrict__ pW2,
                     const float* __restrict__ pW3, float* __restrict__ T) {
  __shared__ float tile[32][33];
  int m = blockIdx.z;
  const float* src = m == 0 ? pW1 : (m == 1 ? pW2 : pW3);
  float* dst = T + m*KD*KD;
  int bx = blockIdx.x*32, by = blockIdx.y*32;
  int tx = threadIdx.x, ty = threadIdx.y;   // block (32,8)
  for (int j = 0; j < 32; j += 8)
    tile[ty + j][tx] = src[(by + ty + j)*KD + bx + tx];
  __syncthreads();
  for (int j = 0; j < 32; j += 8)
    dst[(bx + ty + j)*KD + by + tx] = tile[tx][ty + j];
}

// ---------- register-blocked node GEMM ----------
// MODE 0: hb = bf16(inb@Wa) + fused ss/sd (v1=a_s, v2=a_d); bf16 input; 32 rows/block
// MODE 3: same epilogue, stages fp32 rows gathered from embedding tables; 32 rows/block
// MODE 4: fused head, 16 rows/block: bs=g1[i1], be=g1[NS+i2]; P=sigm(bs@Wa), D=sigm(be@Wb),
//         o=sigm((P-D)@Wc + v1); out[row]=sum(o*v2)/sum(v2). Block 0 wave 0 also
//         finalizes closs from pbuf (passed via sd) -> out[BQ].
template<int MODE>
__global__ __launch_bounds__(256)
void k_ngemm(const unsigned short* __restrict__ inb,
             const float* __restrict__ Wa, const float* __restrict__ Wb,
             const float* __restrict__ Wc,
             const float* __restrict__ v1, const float* __restrict__ v2,
             float* __restrict__ out, unsigned short* __restrict__ hb,
             float* __restrict__ ss, float* __restrict__ sd,
             int nrows,
             const float* __restrict__ g1, const float* __restrict__ g2,
             const float* __restrict__ g3,
             const int* __restrict__ i1, const int* __restrict__ i2,
             const int* __restrict__ i3) {
  constexpr int ROWS = (MODE == 4) ? 16 : 32;   // rows per block
  constexpr int RPW  = ROWS/4;                  // rows per wave
  __shared__ float ers[ROWS][KD];
  __shared__ float xs[(MODE == 4) ? ROWS : 1][KD];
  int t = threadIdx.x;
  int row0 = blockIdx.x * ROWS;
  int w = t >> 6, c = t & 63;

  // ---- stage pass 1 ----
  for (int i = t; i < ROWS*KD; i += 256) {
    int r = i >> 7, k = i & 127;
    int gr = row0 + r;
    float val;
    if (MODE == 3) {
      const float* srow;
      if (gr < NS)           srow = g1 + (size_t)i1[gr]*KD;
      else if (gr < NS + NE) srow = g2 + (size_t)i2[gr - NS]*KD;
      else                   srow = g3 + (size_t)i3[gr - NS - NE]*KD;
      val = srow[k];
    } else if (MODE == 4) {
      val = g1[(size_t)i1[gr]*KD + k];
    } else {
      val = (gr < nrows) ? bf2f_(inb[(size_t)gr*KD + k]) : 0.f;
    }
    ers[r][k] = val;
  }
  __syncthreads();

  float acc0[RPW], acc1[RPW];
  #pragma unroll
  for (int r = 0; r < RPW; r++) { acc0[r] = 0.f; acc1[r] = 0.f; }
  #pragma unroll 2
  for (int kc = 0; kc < KD; kc += 4) {
    float wa[4], wb[4];
    #pragma unroll
    for (int j = 0; j < 4; j++) {
      wa[j] = Wa[(kc + j)*KD + c];
      wb[j] = Wa[(kc + j)*KD + c + 64];
    }
    #pragma unroll
    for (int r = 0; r < RPW; r++) {
      float4 e = *(const float4*)&ers[w*RPW + r][kc];   // wave-uniform broadcast read
      acc0[r] += e.x*wa[0] + e.y*wa[1] + e.z*wa[2] + e.w*wa[3];
      acc1[r] += e.x*wb[0] + e.y*wb[1] + e.z*wb[2] + e.w*wb[3];
    }
  }

  if (MODE == 0 || MODE == 3) {
    float as1 = v1[c], as2 = v1[c + 64], ad1 = v2[c], ad2 = v2[c + 64];
    #pragma unroll
    for (int r = 0; r < RPW; r++) {
      int gr = row0 + w*RPW + r;
      if (gr < nrows) {
        hb[(size_t)gr*KD + c]      = f2b_(acc0[r]);
        hb[(size_t)gr*KD + c + 64] = f2b_(acc1[r]);
      }
      float s = acc0[r]*as1 + acc1[r]*as2;
      float d = acc0[r]*ad1 + acc1[r]*ad2;
      #pragma unroll
      for (int off = 32; off; off >>= 1) { s += __shfl_xor(s, off); d += __shfl_xor(d, off); }
      if (c == 0 && gr < nrows) { ss[gr] = s; sd[gr] = d; }
    }
    return;
  }

  if (MODE == 4) {
    #pragma unroll
    for (int r = 0; r < RPW; r++) {
      xs[w*RPW + r][c]      = sigm_(acc0[r]);
      xs[w*RPW + r][c + 64] = sigm_(acc1[r]);
    }
    __syncthreads();   // all waves done reading ers (GEMM1)
    for (int i = t; i < ROWS*KD; i += 256) {
      int r = i >> 7, k = i & 127;
      int gr = row0 + r;
      ers[r][k] = g1[(size_t)(NS + i2[gr])*KD + k];
    }
    __syncthreads();
    #pragma unroll
    for (int r = 0; r < RPW; r++) { acc0[r] = 0.f; acc1[r] = 0.f; }
    #pragma unroll 2
    for (int kc = 0; kc < KD; kc += 4) {
      float wa[4], wb[4];
      #pragma unroll
      for (int j = 0; j < 4; j++) {
        wa[j] = Wb[(kc + j)*KD + c];
        wb[j] = Wb[(kc + j)*KD + c + 64];
      }
      #pragma unroll
      for (int r = 0; r < RPW; r++) {
        float4 e = *(const float4*)&ers[w*RPW + r][kc];
        acc0[r] += e.x*wa[0] + e.y*wa[1] + e.z*wa[2] + e.w*wa[3];
        acc1[r] += e.x*wb[0] + e.y*wb[1] + e.z*wb[2] + e.w*wb[3];
      }
    }
    #pragma unroll
    for (int r = 0; r < RPW; r++) {     // xs rows are wave-private
      xs[w*RPW + r][c]      -= sigm_(acc0[r]);
      xs[w*RPW + r][c + 64] -= sigm_(acc1[r]);
    }
    #pragma unroll
    for (int r = 0; r < RPW; r++) { acc0[r] = 0.f; acc1[r] = 0.f; }
    #pragma unroll 2
    for (int kc = 0; kc < KD; kc += 4) {
      float wa[4], wb[4];
      #pragma unroll
      for (int j = 0; j < 4; j++) {
        wa[j] = Wc[(kc + j)*KD + c];
        wb[j] = Wc[(kc + j)*KD + c + 64];
      }
      #pragma unroll
      for (int r = 0; r < RPW; r++) {
        float4 e = *(const float4*)&xs[w*RPW + r][kc];
        acc0[r] += e.x*wa[0] + e.y*wa[1] + e.z*wa[2] + e.w*wa[3];
        acc1[r] += e.x*wb[0] + e.y*wb[1] + e.z*wb[2] + e.w*wb[3];
      }
    }
    float b1 = v1[c], b2 = v1[c + 64];
    #pragma unroll
    for (int r = 0; r < RPW; r++) {
      int gr = row0 + w*RPW + r;
      float kr1 = v2[(size_t)gr*KD + c], kr2 = v2[(size_t)gr*KD + c + 64];
      float o1 = sigm_(acc0[r] + b1), o2 = sigm_(acc1[r] + b2);
      float num = o1*kr1 + o2*kr2, den = kr1 + kr2;
      #pragma unroll
      for (int off = 32; off; off >>= 1) { num += __shfl_xor(num, off); den += __shfl_xor(den, off); }
      if (c == 0) out[gr] = num/den;
    }
    // fold-in: finalize closs from pbuf (sd) on block 0, wave 0
    if (blockIdx.x == 0 && w == 0) {
      int lane = t & 63;
      float v = (lane < 32) ? sd[lane] : 0.f;
      #pragma unroll
      for (int off = 32; off; off >>= 1) v += __shfl_xor(v, off);
      if (lane == 0) out[BQ] = 0.1f*v/(float)NS;
    }
  }
}

// ---------- segment-softmax aggregation, SHUFFLE-FREE inner loop ----------
// gsel < 0 : layer 1, 3 graphs batched (shared bf16 h table), bf16 out rows.
// gsel >= 0: layer 2 for graph gsel (per-graph launch, L2-resident slice).
// Each 16-lane subgroup owns a strided edge subset (e += 4); col/ss loads are
// subgroup-broadcast, exp redundantly computed -> zero cross-lane ops in the
// loop, iterations fully independent (only accumulators carry). l ends
// identical within a subgroup; xor16/32 reduces across subgroups.
__global__ __launch_bounds__(256)
void k_agg(const int* __restrict__ rp_all, const unsigned short* __restrict__ col_all,
           const unsigned short* __restrict__ hb_base, const float* __restrict__ ss,
           const float* __restrict__ sd, unsigned short* __restrict__ outb,
           float* __restrict__ out, unsigned short* __restrict__ Zo, int gsel) {
  int wv = blockIdx.x*4 + (threadIdx.x >> 6);
  int lane = threadIdx.x & 63;
  int g, node;
  if (gsel < 0) {
    if (wv >= 3*NNODE) return;
    g = wv / NNODE; node = wv - g*NNODE;
  } else {
    g = gsel; node = wv;
    if (node >= NS + NE) return;
  }
  const int* rp = rp_all + g*RP;
  const unsigned short* cl = col_all + (size_t)g*NCSR;
  const unsigned short* hgb = (gsel < 0) ? hb_base : hb_base + (size_t)g*NNODE*KD;
  const float* ssg = (gsel < 0) ? ss : ss + g*NNODE;
  const float* sdg = (gsel < 0) ? sd : sd + g*NNODE;
  int e0 = rp[node], e1 = rp[node + 1];
  float sdv = sdg[node];
  int sub = lane >> 4;       // edge subgroup 0..3
  int fl  = lane & 15;       // feature lane: features fl*8 .. fl*8+7
  float l = 0.f;
  float A[8] = {0,0,0,0,0,0,0,0};
  #pragma unroll 4
  for (int e = e0 + sub; e < e1; e += 4) {
    int o = cl[e];                               // subgroup-uniform (broadcast)
    float pj = __expf(lrelu_(ssg[o] + sdv));     // redundant per subgroup, VALU-cheap
    l += pj;
    short8 mv = *(const short8*)&hgb[(size_t)o*KD + fl*8];   // 16 lanes x 16B = 256B row
    #pragma unroll
    for (int q = 0; q < 8; q++)
      A[q] += pj * bf2f_((unsigned short)mv[q]);
  }
  // cross-subgroup reduce (l identical within subgroup; A partial per subgroup)
  l += __shfl_xor(l, 16); l += __shfl_xor(l, 32);
  #pragma unroll
  for (int q = 0; q < 8; q++) {
    A[q] += __shfl_xor(A[q], 16);
    A[q] += __shfl_xor(A[q], 32);
  }
  float inv = 1.f/(l + 1e-16f);
  float av[8];
  #pragma unroll
  for (int q = 0; q < 8; q++) av[q] = elu_(A[q]*inv);
  if (gsel < 0) {
    if (sub == 0) {
      short8 sv;
      #pragma unroll
      for (int q = 0; q < 8; q++) sv[q] = (short)f2b_(av[q]);
      *(short8*)&outb[(size_t)wv*KD + fl*8] = sv;
    }
    return;
  }
  if (g == 0) {
    if (sub == 0) {
      float* orow = &out[(size_t)node*KD + fl*8];
      *(float4*)orow       = make_float4(av[0], av[1], av[2], av[3]);
      *(float4*)(orow + 4) = make_float4(av[4], av[5], av[6], av[7]);
    }
  } else {
    float nrm = av[0]*av[0] + av[1]*av[1] + av[2]*av[2] + av[3]*av[3]
              + av[4]*av[4] + av[5]*av[5] + av[6]*av[6] + av[7]*av[7];
    #pragma unroll
    for (int off = 1; off <= 8; off <<= 1) nrm += __shfl_xor(nrm, off);
    float invn = 1.f/(sqrtf(nrm) + 1e-12f);
    if (sub == 0) {
      short8 sv;
      #pragma unroll
      for (int q = 0; q < 8; q++) sv[q] = (short)f2b_(av[q]*invn);
      *(short8*)&Zo[((size_t)(g - 1)*8192 + node)*KD + fl*8] = sv;
    }
  }
}

// ---------- bf16 MFMA similarity GEMM, atomic-free partial-sum epilogue ----------
// grid (32,32,2). rsp/csp: [2][64][NS] partials, unique writer per element.
__global__ __launch_bounds__(256)
void k_sim(const unsigned short* __restrict__ Z, float* __restrict__ rsp,
           float* __restrict__ csp, float* __restrict__ dg_all) {
  __shared__ unsigned short As[128*KD];   // 32 KB, row r: 16 groups of 8, group g at (g ^ (r&15))
  __shared__ unsigned short Bs[128*KD];   // 32 KB
  int z = blockIdx.z;
  int t = threadIdx.x;
  const unsigned short* Arow = Z + ((size_t)z*NS + (size_t)blockIdx.x*128)*KD;
  const unsigned short* Brow = Z + ((size_t)8192 + (size_t)z*NS + (size_t)blockIdx.y*128)*KD;
  #pragma unroll
  for (int j = 0; j < 8; j++) {
    int G = t + j*256;                     // linear 16B-group id, 0..2047
    int r = G >> 4, g = G & 15;
    int sw = g ^ (r & 15);
    *(float4*)&As[(r*16 + sw)*8] = *(const float4*)&Arow[(size_t)G*8];
    *(float4*)&Bs[(r*16 + sw)*8] = *(const float4*)&Brow[(size_t)G*8];
  }
  __syncthreads();
  int w = t >> 6, lane = t & 63;
  int rw = (w >> 1)*64, cw = (w & 1)*64;
  int m15 = lane & 15, quad = lane >> 4;
  float4_ acc[4][4] = {};
  #pragma unroll
  for (int kq = 0; kq < 4; kq++) {
    short8 a[4], b[4];
    int g = kq*4 + quad;
    #pragma unroll
    for (int mi = 0; mi < 4; mi++) {
      int r = rw + mi*16 + m15;
      a[mi] = *(const short8*)&As[(r*16 + (g ^ (r & 15)))*8];
    }
    #pragma unroll
    for (int ni = 0; ni < 4; ni++) {
      int r = cw + ni*16 + m15;
      b[ni] = *(const short8*)&Bs[(r*16 + (g ^ (r & 15)))*8];
    }
    #pragma unroll
    for (int mi = 0; mi < 4; mi++)
      #pragma unroll
      for (int ni = 0; ni < 4; ni++)
        acc[mi][ni] = __builtin_amdgcn_mfma_f32_16x16x32_bf16(a[mi], b[ni], acc[mi][ni], 0, 0, 0);
  }
  int i0 = blockIdx.x*128, j0 = blockIdx.y*128;
  float* diag = dg_all + z*NS;
  float* rrow = rsp + ((size_t)z*64 + blockIdx.y*2 + (w & 1))*NS;
  float* crow = csp + ((size_t)z*64 + blockIdx.x*2 + (w >> 1))*NS;
  float cs[4] = {0,0,0,0};
  #pragma unroll
  for (int mi = 0; mi < 4; mi++) {
    float rs[4] = {0,0,0,0};
    #pragma unroll
    for (int ni = 0; ni < 4; ni++) {
      #pragma unroll
      for (int reg = 0; reg < 4; reg++) {
        float sim2 = acc[mi][ni][reg]*2.0f;
        int gi = i0 + rw + mi*16 + quad*4 + reg;     // C/D: row=(lane>>4)*4+reg
        int gj = j0 + cw + ni*16 + m15;              //      col=lane&15
        if (gi == gj) diag[gi] = sim2;
        float e = __expf(sim2);
        rs[reg] += e; cs[ni] += e;
      }
    }
    #pragma unroll
    for (int reg = 0; reg < 4; reg++) {
      float v = rs[reg];
      v += __shfl_xor(v, 1); v += __shfl_xor(v, 2);
      v += __shfl_xor(v, 4); v += __shfl_xor(v, 8);
      if (m15 == 0) rrow[i0 + rw + mi*16 + quad*4 + reg] = v;
    }
  }
  #pragma unroll
  for (int ni = 0; ni < 4; ni++) {
    float v = cs[ni];
    v += __shfl_xor(v, 16); v += __shfl_xor(v, 32);
    if (quad == 0) crow[j0 + cw + ni*16 + m15] = v;
  }
}

// reduce partials -> per-block loss partial (grid (16,2))
__global__ void k_lred(const float* __restrict__ rsp, const float* __restrict__ csp,
                       const float* __restrict__ dg_all, float* __restrict__ pbuf) {
  __shared__ float red[256];
  int z = blockIdx.y;
  int i = blockIdx.x*256 + threadIdx.x;
  float rs = 0.f, cs = 0.f;
  for (int s = 0; s < 64; s++) {
    rs += rsp[((size_t)z*64 + s)*NS + i];
    cs += csp[((size_t)z*64 + s)*NS + i];
  }
  float v = logf(rs) + logf(cs) - 2.f*dg_all[z*NS + i];
  red[threadIdx.x] = v; __syncthreads();
  for (int off = 128; off; off >>= 1) {
    if (threadIdx.x < off) red[threadIdx.x] += red[threadIdx.x + off];
    __syncthreads();
  }
  if (threadIdx.x == 0) pbuf[z*16 + blockIdx.x] = red[0];
}

extern "C" void kernel_launch(void* const* d_in, const int* in_sizes, int n_in,
                              void* d_out, int out_size, void* d_ws, size_t ws_size,
                              hipStream_t stream) {
  const float* E_stu  = (const float*)d_in[0];
  const float* E_exer = (const float*)d_in[1];
  const float* E_k    = (const float*)d_in[2];
  const float* W1  = (const float*)d_in[3];
  const float* a1s = (const float*)d_in[4];
  const float* a1d = (const float*)d_in[5];
  const float* W2  = (const float*)d_in[6];
  const float* a2s = (const float*)d_in[7];
  const float* a2d = (const float*)d_in[8];
  const float* pW1 = (const float*)d_in[9];
  const float* pW2 = (const float*)d_in[10];
  const float* pW3 = (const float*)d_in[11];
  const float* pb3 = (const float*)d_in[12];
  const float* kn_r = (const float*)d_in[13];
  const int* stu_ids  = (const int*)d_in[14];
  const int* exer_ids = (const int*)d_in[15];
  const int* k_ids    = (const int*)d_in[16];
  EdgePtrs ep;
  for (int g = 0; g < 3; g++) {
    ep.s_src[g] = (const int*)d_in[17 + g*4];
    ep.s_dst[g] = (const int*)d_in[18 + g*4];
    ep.e_src[g] = (const int*)d_in[19 + g*4];
    ep.e_dst[g] = (const int*)d_in[20 + g*4];
  }
  const int* stu_index  = (const int*)d_in[29];
  const int* exer_index = (const int*)d_in[30];
  float* out = (float*)d_out;   // [0..8191] predictions, [8192] closs

  // ---- workspace carve ----
  char* p = (char*)d_ws;
  auto carve = [&](size_t bytes) -> char* {
    char* r = p; p += (bytes + 255) & ~(size_t)255; return r;
  };
  const size_t NODE_F = (size_t)NNODE*KD;
  float* ssb = (float*)carve((size_t)8*NNODE*4);
  float* ss0 = ssb,            *sd0 = ssb + NNODE;
  float* ss3 = ssb + 2*NNODE,  *sd3 = ssb + 5*NNODE;
  unsigned short* hb0 = (unsigned short*)carve(NODE_F*2);        // layer-1 h (shared)
  unsigned short* hb3 = (unsigned short*)carve(3*NODE_F*2);      // layer-2 h x3
  // time-multiplexed: CSR partials (6.4 MB) -> layer-1 agg bf16 out (6.4 MB)
  char* Creg = carve((size_t)8*HB*NNODE*4);
  int*   part = (int*)Creg;                       // part[3][HB][NNODE]
  int*   boff = (int*)Creg + (size_t)3*HB*NNODE;  // boff[3][HB][NNODE]
  unsigned short* etb = (unsigned short*)Creg;    // layer-1 agg out, bf16 [3*NNODE][KD]
  float* eoutAll = (float*)carve((size_t)(NS + NE)*KD*4);        // main-graph layer-2 out
  int* cnt_all = (int*)carve((size_t)3*NNODE*4);
  int* rp_all  = (int*)carve((size_t)3*RP*4);
  unsigned short* col_all = (unsigned short*)carve((size_t)3*NCSR*2);
  float* pWT = (float*)carve((size_t)3*KD*KD*4);
  float* pW1T = pWT, *pW2T = pWT + KD*KD, *pW3T = pWT + 2*KD*KD;
  float* rsp = (float*)carve((size_t)2*64*NS*4);   // rowsum partials
  float* csp = (float*)carve((size_t)2*64*NS*4);   // colsum partials
  float* dg_all = (float*)carve((size_t)2*NS*4);
  float* pbuf = (float*)carve(64*4);
  unsigned short* Z = (unsigned short*)carve((size_t)2*8192*KD*2);  // bf16 Z1|Z2

  // ---- CSR build (atomic-free, all stages parallel) + weight transpose ----
  k_hist<<<dim3(HB, 3), 256, 0, stream>>>(ep, part);
  k_sumpart<<<(3*NNODE + 255)/256, 256, 0, stream>>>(part, cnt_all);
  k_scan<<<3, 1024, 0, stream>>>(cnt_all, rp_all);
  k_boff<<<(3*NNODE + 255)/256, 256, 0, stream>>>(part, rp_all, boff);
  k_scatter<<<dim3(HB, 3), 256, 0, stream>>>(ep, boff, col_all);
  k_tr<<<dim3(4, 4, 3), dim3(32, 8), 0, stream>>>(pW1, pW2, pW3, pWT);

  // ---- GAT layer 1 (h shared across graphs; embedding gather fused; bf16 h) ----
  k_ngemm<3><<<NNODE/32, 256, 0, stream>>>(nullptr, W1, nullptr, nullptr, a1s, a1d,
                                           nullptr, hb0, ss0, sd0, NNODE,
                                           E_stu, E_exer, E_k, stu_ids, exer_ids, k_ids);
  k_agg<<<3*NNODE/4, 256, 0, stream>>>(rp_all, col_all, hb0, ss0, sd0, etb,
                                       nullptr, nullptr, -1);

  // ---- GAT layer 2 (bf16 input; per-graph agg launches for L2 residency) ----
  k_ngemm<0><<<3*NNODE/32, 256, 0, stream>>>(etb, W2, nullptr, nullptr, a2s, a2d,
                                             nullptr, hb3, ss3, sd3, 3*NNODE,
                                             nullptr, nullptr, nullptr, nullptr, nullptr, nullptr);
  for (int g = 0; g < 3; g++)
    k_agg<<<(NS + NE)/4, 256, 0, stream>>>(rp_all, col_all, hb3, ss3, sd3, nullptr,
                                           eoutAll, Z, g);

  // ---- contrastive loss (bf16 MFMA sim, atomic-free epilogue) ----
  k_sim<<<dim3(32, 32, 2), 256, 0, stream>>>(Z, rsp, csp, dg_all);
  k_lred<<<dim3(16, 2), 256, 0, stream>>>(rsp, csp, dg_all, pbuf);

  // ---- prediction head (fused; block 0 also finalizes closs from pbuf) ----
  k_ngemm<4><<<BQ/16, 256, 0, stream>>>(nullptr, pW1T, pW2T, pW3T, pb3, kn_r,
                                        out, nullptr, nullptr, pbuf, BQ,
                                        eoutAll, nullptr, nullptr, stu_index, exer_index, nullptr);
}

// Round 13
// 316.989 us; speedup vs baseline: 1.2542x; 1.0543x over previous
//
#include <hip/hip_runtime.h>
#include <hip/hip_bf16.h>
#include <math.h>

#define KD 128
#define NS 4096
#define NE 4096
#define NK 128
#define NNODE (NS + NE + NK)      // 8320
#define ESE 131072
#define EEK 16384
#define NCSR (2*ESE + 2*EEK)      // 294912
#define BQ 8192
#define RP (NNODE + 1)
#define HB 32                     // CSR-build blocks per graph

typedef __attribute__((ext_vector_type(8))) short short8;   // 8 bf16 (4 VGPRs)
typedef __attribute__((ext_vector_type(4))) float float4_;  // 4 fp32 acc

__device__ __forceinline__ float lrelu_(float x){ return x >= 0.f ? x : 0.2f*x; }
__device__ __forceinline__ float elu_(float x){ return x > 0.f ? x : __expf(x) - 1.f; }
__device__ __forceinline__ float sigm_(float x){ return 1.f/(1.f + __expf(-x)); }
__device__ __forceinline__ float bf2f_(unsigned short u){
  union { unsigned int i; float f; } v; v.i = ((unsigned int)u) << 16; return v.f;
}
__device__ __forceinline__ unsigned short f2b_(float x){
  __hip_bfloat16 b = __float2bfloat16(x); return *(unsigned short*)&b;
}

struct EdgePtrs { const int* s_src[3]; const int* s_dst[3]; const int* e_src[3]; const int* e_dst[3]; };

// ================= fused independent-phase kernel =================
// blocks [0,96):   CSR histogram (LDS, no global atomics)       -> part
// blocks [96,356): layer-1 node GEMM (embedding gather fused)   -> hb0/ss0/sd0
// blocks [356,404): head weight transpose                       -> pWT
// All three read/write disjoint buffers; branch is block-uniform.
__global__ __launch_bounds__(256)
void k_fuse1(EdgePtrs ep, int* __restrict__ part,
             const float* __restrict__ W1, const float* __restrict__ a1s,
             const float* __restrict__ a1d,
             unsigned short* __restrict__ hb0, float* __restrict__ ss0,
             float* __restrict__ sd0,
             const float* __restrict__ E_stu, const float* __restrict__ E_exer,
             const float* __restrict__ E_k, const int* __restrict__ sid,
             const int* __restrict__ eid, const int* __restrict__ kid,
             const float* __restrict__ pW1, const float* __restrict__ pW2,
             const float* __restrict__ pW3, float* __restrict__ pWT) {
  __shared__ __align__(16) char smem[NNODE*4];   // 33 KB union
  int bid = blockIdx.x, t = threadIdx.x;

  if (bid < 3*HB) {
    // ---- CSR histogram ----
    int* hcnt = (int*)smem;
    int g = bid / HB, b = bid % HB;
    for (int i = t; i < NNODE; i += 256) hcnt[i] = 0;
    __syncthreads();
    const int* ss_ = ep.s_src[g]; const int* sd_ = ep.s_dst[g];
    const int* es_ = ep.e_src[g]; const int* ed_ = ep.e_dst[g];
    int se0 = b*(ESE/HB);
    for (int i = se0 + t; i < se0 + ESE/HB; i += 256) {
      atomicAdd(&hcnt[ss_[i]], 1);
      atomicAdd(&hcnt[NS + sd_[i]], 1);
    }
    int ek0 = b*(EEK/HB);
    for (int i = ek0 + t; i < ek0 + EEK/HB; i += 256) {
      atomicAdd(&hcnt[NS + es_[i]], 1);
      atomicAdd(&hcnt[NS + NE + ed_[i]], 1);
    }
    __syncthreads();
    int* pp = part + ((size_t)g*HB + b)*NNODE;
    for (int i = t; i < NNODE; i += 256) pp[i] = hcnt[i];
    return;
  }

  if (bid < 3*HB + NNODE/32) {
    // ---- layer-1 node GEMM (MODE-3 body) ----
    float (*ers)[KD] = (float(*)[KD])smem;       // 16 KB of the union
    int row0 = (bid - 3*HB)*32;
    int w = t >> 6, c = t & 63;
    for (int i = t; i < 32*KD; i += 256) {
      int r = i >> 7, k = i & 127;
      int gr = row0 + r;
      const float* srow;
      if (gr < NS)           srow = E_stu  + (size_t)sid[gr]*KD;
      else if (gr < NS + NE) srow = E_exer + (size_t)eid[gr - NS]*KD;
      else                   srow = E_k    + (size_t)kid[gr - NS - NE]*KD;
      ers[r][k] = srow[k];
    }
    __syncthreads();
    float acc0[8] = {0,0,0,0,0,0,0,0}, acc1[8] = {0,0,0,0,0,0,0,0};
    #pragma unroll 2
    for (int kc = 0; kc < KD; kc += 4) {
      float wa[4], wb[4];
      #pragma unroll
      for (int j = 0; j < 4; j++) {
        wa[j] = W1[(kc + j)*KD + c];
        wb[j] = W1[(kc + j)*KD + c + 64];
      }
      #pragma unroll
      for (int r = 0; r < 8; r++) {
        float4 e = *(const float4*)&ers[w*8 + r][kc];
        acc0[r] += e.x*wa[0] + e.y*wa[1] + e.z*wa[2] + e.w*wa[3];
        acc1[r] += e.x*wb[0] + e.y*wb[1] + e.z*wb[2] + e.w*wb[3];
      }
    }
    float as1 = a1s[c], as2 = a1s[c + 64], ad1 = a1d[c], ad2 = a1d[c + 64];
    #pragma unroll
    for (int r = 0; r < 8; r++) {
      int gr = row0 + w*8 + r;
      hb0[(size_t)gr*KD + c]      = f2b_(acc0[r]);
      hb0[(size_t)gr*KD + c + 64] = f2b_(acc1[r]);
      float s = acc0[r]*as1 + acc1[r]*as2;
      float d = acc0[r]*ad1 + acc1[r]*ad2;
      #pragma unroll
      for (int off = 32; off; off >>= 1) { s += __shfl_xor(s, off); d += __shfl_xor(d, off); }
      if (c == 0) { ss0[gr] = s; sd0[gr] = d; }
    }
    return;
  }

  // ---- head weight transpose (flat-threaded) ----
  {
    float (*tile)[33] = (float(*)[33])smem;
    int idx = bid - 3*HB - NNODE/32;             // 0..47
    int m = idx >> 4, rem = idx & 15;
    int bx = (rem & 3)*32, by = (rem >> 2)*32;
    const float* src = m == 0 ? pW1 : (m == 1 ? pW2 : pW3);
    float* dst = pWT + m*KD*KD;
    int tx = t & 31, ty = t >> 5;                // (32,8) mapping
    for (int j = 0; j < 32; j += 8)
      tile[ty + j][tx] = src[(by + ty + j)*KD + bx + tx];
    __syncthreads();
    for (int j = 0; j < 32; j += 8)
      dst[(bx + ty + j)*KD + by + tx] = tile[tx][ty + j];
  }
}

// thread-per-node partial-sum: cnt[g][n] = sum_b part[g][b][n]  (coalesced over n)
__global__ void k_sumpart(const int* __restrict__ part, int* __restrict__ cnt_all) {
  int idx = blockIdx.x*256 + threadIdx.x;
  if (idx >= 3*NNODE) return;
  int g = idx / NNODE, n = idx - g*NNODE;
  const int* pg = part + (size_t)g*HB*NNODE + n;
  int s = 0;
  #pragma unroll
  for (int b = 0; b < HB; b++) s += pg[(size_t)b*NNODE];
  cnt_all[idx] = s;
}

// per-graph single-block scan of cnt -> row_ptr (lightweight: 9 reads/thread)
__global__ void k_scan(const int* __restrict__ cnt_all, int* __restrict__ rp_all) {
  __shared__ int sums[1024];
  const int CH = (NNODE + 1023) / 1024;    // 9
  int g = blockIdx.x, t = threadIdx.x;
  const int* cnt = cnt_all + g*NNODE;
  int* row_ptr = rp_all + g*RP;
  int base = t*CH;
  int local[CH];
  int s = 0;
  for (int j = 0; j < CH; j++) {
    int v = (base + j < NNODE) ? cnt[base + j] : 0;
    local[j] = s; s += v;
  }
  sums[t] = s; __syncthreads();
  for (int off = 1; off < 1024; off <<= 1) {
    int v = (t >= off) ? sums[t - off] : 0;
    __syncthreads();
    sums[t] += v;
    __syncthreads();
  }
  int excl = (t == 0) ? 0 : sums[t - 1];
  for (int j = 0; j < CH; j++)
    if (base + j < NNODE) row_ptr[base + j] = excl + local[j];
  if (t == 1023) row_ptr[NNODE] = sums[1023];
}

// thread-per-node: emit per-block cursors boff[g][b][n] (coalesced over n)
__global__ void k_boff(const int* __restrict__ part, const int* __restrict__ rp_all,
                       int* __restrict__ boff) {
  int idx = blockIdx.x*256 + threadIdx.x;
  if (idx >= 3*NNODE) return;
  int g = idx / NNODE, n = idx - g*NNODE;
  const int* pg = part + (size_t)g*HB*NNODE + n;
  int* bg = boff + (size_t)g*HB*NNODE + n;
  int acc = rp_all[g*RP + n];
  #pragma unroll
  for (int b = 0; b < HB; b++) {
    bg[(size_t)b*NNODE] = acc;
    acc += pg[(size_t)b*NNODE];
  }
}

// scatter via LDS cursors initialized from boff (no global atomics); col stored ushort
__global__ __launch_bounds__(256)
void k_scatter(EdgePtrs ep, const int* __restrict__ boff, unsigned short* __restrict__ col_all) {
  __shared__ int cur[NNODE];      // 33 KB live cursors
  int g = blockIdx.y, b = blockIdx.x, t = threadIdx.x;
  const int* bg = boff + ((size_t)g*HB + b)*NNODE;
  for (int i = t; i < NNODE; i += 256) cur[i] = bg[i];
  __syncthreads();
  const int* ss_ = ep.s_src[g]; const int* sd_ = ep.s_dst[g];
  const int* es_ = ep.e_src[g]; const int* ed_ = ep.e_dst[g];
  unsigned short* col = col_all + (size_t)g*NCSR;
  int se0 = b*(ESE/HB);
  for (int i = se0 + t; i < se0 + ESE/HB; i += 256) {
    int s = ss_[i], d = NS + sd_[i];
    col[atomicAdd(&cur[s], 1)] = (unsigned short)d;
    col[atomicAdd(&cur[d], 1)] = (unsigned short)s;
  }
  int ek0 = b*(EEK/HB);
  for (int i = ek0 + t; i < ek0 + EEK/HB; i += 256) {
    int s = NS + es_[i], d = NS + NE + ed_[i];
    col[atomicAdd(&cur[s], 1)] = (unsigned short)d;
    col[atomicAdd(&cur[d], 1)] = (unsigned short)s;
  }
}

// ---------- register-blocked node GEMM ----------
// MODE 0: hb = bf16(inb@Wa) + fused ss/sd (v1=a_s, v2=a_d); bf16 input; 32 rows/block
// MODE 4: fused head, 16 rows/block: bs=g1[i1], be=g1[NS+i2]; P=sigm(bs@Wa), D=sigm(be@Wb),
//         o=sigm((P-D)@Wc + v1); out[row]=sum(o*v2)/sum(v2). Block 0 wave 0 also
//         finalizes closs from pbuf (passed via sd) -> out[BQ].
template<int MODE>
__global__ __launch_bounds__(256)
void k_ngemm(const unsigned short* __restrict__ inb,
             const float* __restrict__ Wa, const float* __restrict__ Wb,
             const float* __restrict__ Wc,
             const float* __restrict__ v1, const float* __restrict__ v2,
             float* __restrict__ out, unsigned short* __restrict__ hb,
             float* __restrict__ ss, float* __restrict__ sd,
             int nrows,
             const float* __restrict__ g1,
             const int* __restrict__ i1, const int* __restrict__ i2) {
  constexpr int ROWS = (MODE == 4) ? 16 : 32;   // rows per block
  constexpr int RPW  = ROWS/4;                  // rows per wave
  __shared__ float ers[ROWS][KD];
  __shared__ float xs[(MODE == 4) ? ROWS : 1][KD];
  int t = threadIdx.x;
  int row0 = blockIdx.x * ROWS;
  int w = t >> 6, c = t & 63;

  for (int i = t; i < ROWS*KD; i += 256) {
    int r = i >> 7, k = i & 127;
    int gr = row0 + r;
    float val;
    if (MODE == 4) val = g1[(size_t)i1[gr]*KD + k];
    else           val = (gr < nrows) ? bf2f_(inb[(size_t)gr*KD + k]) : 0.f;
    ers[r][k] = val;
  }
  __syncthreads();

  float acc0[RPW], acc1[RPW];
  #pragma unroll
  for (int r = 0; r < RPW; r++) { acc0[r] = 0.f; acc1[r] = 0.f; }
  #pragma unroll 2
  for (int kc = 0; kc < KD; kc += 4) {
    float wa[4], wb[4];
    #pragma unroll
    for (int j = 0; j < 4; j++) {
      wa[j] = Wa[(kc + j)*KD + c];
      wb[j] = Wa[(kc + j)*KD + c + 64];
    }
    #pragma unroll
    for (int r = 0; r < RPW; r++) {
      float4 e = *(const float4*)&ers[w*RPW + r][kc];   // wave-uniform broadcast read
      acc0[r] += e.x*wa[0] + e.y*wa[1] + e.z*wa[2] + e.w*wa[3];
      acc1[r] += e.x*wb[0] + e.y*wb[1] + e.z*wb[2] + e.w*wb[3];
    }
  }

  if (MODE == 0) {
    float as1 = v1[c], as2 = v1[c + 64], ad1 = v2[c], ad2 = v2[c + 64];
    #pragma unroll
    for (int r = 0; r < RPW; r++) {
      int gr = row0 + w*RPW + r;
      if (gr < nrows) {
        hb[(size_t)gr*KD + c]      = f2b_(acc0[r]);
        hb[(size_t)gr*KD + c + 64] = f2b_(acc1[r]);
      }
      float s = acc0[r]*as1 + acc1[r]*as2;
      float d = acc0[r]*ad1 + acc1[r]*ad2;
      #pragma unroll
      for (int off = 32; off; off >>= 1) { s += __shfl_xor(s, off); d += __shfl_xor(d, off); }
      if (c == 0 && gr < nrows) { ss[gr] = s; sd[gr] = d; }
    }
    return;
  }

  if (MODE == 4) {
    #pragma unroll
    for (int r = 0; r < RPW; r++) {
      xs[w*RPW + r][c]      = sigm_(acc0[r]);
      xs[w*RPW + r][c + 64] = sigm_(acc1[r]);
    }
    __syncthreads();   // all waves done reading ers (GEMM1)
    for (int i = t; i < ROWS*KD; i += 256) {
      int r = i >> 7, k = i & 127;
      int gr = row0 + r;
      ers[r][k] = g1[(size_t)(NS + i2[gr])*KD + k];
    }
    __syncthreads();
    #pragma unroll
    for (int r = 0; r < RPW; r++) { acc0[r] = 0.f; acc1[r] = 0.f; }
    #pragma unroll 2
    for (int kc = 0; kc < KD; kc += 4) {
      float wa[4], wb[4];
      #pragma unroll
      for (int j = 0; j < 4; j++) {
        wa[j] = Wb[(kc + j)*KD + c];
        wb[j] = Wb[(kc + j)*KD + c + 64];
      }
      #pragma unroll
      for (int r = 0; r < RPW; r++) {
        float4 e = *(const float4*)&ers[w*RPW + r][kc];
        acc0[r] += e.x*wa[0] + e.y*wa[1] + e.z*wa[2] + e.w*wa[3];
        acc1[r] += e.x*wb[0] + e.y*wb[1] + e.z*wb[2] + e.w*wb[3];
      }
    }
    #pragma unroll
    for (int r = 0; r < RPW; r++) {     // xs rows are wave-private
      xs[w*RPW + r][c]      -= sigm_(acc0[r]);
      xs[w*RPW + r][c + 64] -= sigm_(acc1[r]);
    }
    #pragma unroll
    for (int r = 0; r < RPW; r++) { acc0[r] = 0.f; acc1[r] = 0.f; }
    #pragma unroll 2
    for (int kc = 0; kc < KD; kc += 4) {
      float wa[4], wb[4];
      #pragma unroll
      for (int j = 0; j < 4; j++) {
        wa[j] = Wc[(kc + j)*KD + c];
        wb[j] = Wc[(kc + j)*KD + c + 64];
      }
      #pragma unroll
      for (int r = 0; r < RPW; r++) {
        float4 e = *(const float4*)&xs[w*RPW + r][kc];
        acc0[r] += e.x*wa[0] + e.y*wa[1] + e.z*wa[2] + e.w*wa[3];
        acc1[r] += e.x*wb[0] + e.y*wb[1] + e.z*wb[2] + e.w*wb[3];
      }
    }
    float b1 = v1[c], b2 = v1[c + 64];
    #pragma unroll
    for (int r = 0; r < RPW; r++) {
      int gr = row0 + w*RPW + r;
      float kr1 = v2[(size_t)gr*KD + c], kr2 = v2[(size_t)gr*KD + c + 64];
      float o1 = sigm_(acc0[r] + b1), o2 = sigm_(acc1[r] + b2);
      float num = o1*kr1 + o2*kr2, den = kr1 + kr2;
      #pragma unroll
      for (int off = 32; off; off >>= 1) { num += __shfl_xor(num, off); den += __shfl_xor(den, off); }
      if (c == 0) out[gr] = num/den;
    }
    if (blockIdx.x == 0 && w == 0) {
      int lane = t & 63;
      float v = (lane < 32) ? sd[lane] : 0.f;
      #pragma unroll
      for (int off = 32; off; off >>= 1) v += __shfl_xor(v, off);
      if (lane == 0) out[BQ] = 0.1f*v/(float)NS;
    }
  }
}

// ---------- segment-softmax aggregation, SHUFFLE-FREE inner loop ----------
// gsel == -1: layer 1, 3 graphs batched (shared bf16 h table), bf16 out rows.
// gsel == -2: layer 2, 3 graphs batched (per-graph h slices); skip k rows;
//             g0 -> fp32 out, g1/g2 -> normalized bf16 Z.
__global__ __launch_bounds__(256)
void k_agg(const int* __restrict__ rp_all, const unsigned short* __restrict__ col_all,
           const unsigned short* __restrict__ hb_base, const float* __restrict__ ss,
           const float* __restrict__ sd, unsigned short* __restrict__ outb,
           float* __restrict__ out, unsigned short* __restrict__ Zo, int gsel) {
  int wv = blockIdx.x*4 + (threadIdx.x >> 6);
  int lane = threadIdx.x & 63;
  if (wv >= 3*NNODE) return;
  int g = wv / NNODE, node = wv - g*NNODE;
  bool layer2 = (gsel == -2);
  if (layer2 && node >= NS + NE) return;        // k rows unused after layer 2
  const int* rp = rp_all + g*RP;
  const unsigned short* cl = col_all + (size_t)g*NCSR;
  const unsigned short* hgb = layer2 ? hb_base + (size_t)g*NNODE*KD : hb_base;
  const float* ssg = layer2 ? ss + g*NNODE : ss;
  const float* sdg = layer2 ? sd + g*NNODE : sd;
  int e0 = rp[node], e1 = rp[node + 1];
  float sdv = sdg[node];
  int sub = lane >> 4;       // edge subgroup 0..3
  int fl  = lane & 15;       // feature lane: features fl*8 .. fl*8+7
  float l = 0.f;
  float A[8] = {0,0,0,0,0,0,0,0};
  #pragma unroll 4
  for (int e = e0 + sub; e < e1; e += 4) {
    int o = cl[e];                               // subgroup-uniform (broadcast)
    float pj = __expf(lrelu_(ssg[o] + sdv));     // redundant per subgroup, VALU-cheap
    l += pj;
    short8 mv = *(const short8*)&hgb[(size_t)o*KD + fl*8];   // 16 lanes x 16B = 256B row
    #pragma unroll
    for (int q = 0; q < 8; q++)
      A[q] += pj * bf2f_((unsigned short)mv[q]);
  }
  l += __shfl_xor(l, 16); l += __shfl_xor(l, 32);
  #pragma unroll
  for (int q = 0; q < 8; q++) {
    A[q] += __shfl_xor(A[q], 16);
    A[q] += __shfl_xor(A[q], 32);
  }
  float inv = 1.f/(l + 1e-16f);
  float av[8];
  #pragma unroll
  for (int q = 0; q < 8; q++) av[q] = elu_(A[q]*inv);
  if (!layer2) {
    if (sub == 0) {
      short8 sv;
      #pragma unroll
      for (int q = 0; q < 8; q++) sv[q] = (short)f2b_(av[q]);
      *(short8*)&outb[(size_t)wv*KD + fl*8] = sv;
    }
    return;
  }
  if (g == 0) {
    if (sub == 0) {
      float* orow = &out[(size_t)node*KD + fl*8];
      *(float4*)orow       = make_float4(av[0], av[1], av[2], av[3]);
      *(float4*)(orow + 4) = make_float4(av[4], av[5], av[6], av[7]);
    }
  } else {
    float nrm = av[0]*av[0] + av[1]*av[1] + av[2]*av[2] + av[3]*av[3]
              + av[4]*av[4] + av[5]*av[5] + av[6]*av[6] + av[7]*av[7];
    #pragma unroll
    for (int off = 1; off <= 8; off <<= 1) nrm += __shfl_xor(nrm, off);
    float invn = 1.f/(sqrtf(nrm) + 1e-12f);
    if (sub == 0) {
      short8 sv;
      #pragma unroll
      for (int q = 0; q < 8; q++) sv[q] = (short)f2b_(av[q]*invn);
      *(short8*)&Zo[((size_t)(g - 1)*8192 + node)*KD + fl*8] = sv;
    }
  }
}

// ---------- bf16 MFMA similarity GEMM, atomic-free partial-sum epilogue ----------
__global__ __launch_bounds__(256)
void k_sim(const unsigned short* __restrict__ Z, float* __restrict__ rsp,
           float* __restrict__ csp, float* __restrict__ dg_all) {
  __shared__ unsigned short As[128*KD];   // 32 KB, row r: 16 groups of 8, group g at (g ^ (r&15))
  __shared__ unsigned short Bs[128*KD];   // 32 KB
  int z = blockIdx.z;
  int t = threadIdx.x;
  const unsigned short* Arow = Z + ((size_t)z*NS + (size_t)blockIdx.x*128)*KD;
  const unsigned short* Brow = Z + ((size_t)8192 + (size_t)z*NS + (size_t)blockIdx.y*128)*KD;
  #pragma unroll
  for (int j = 0; j < 8; j++) {
    int G = t + j*256;                     // linear 16B-group id, 0..2047
    int r = G >> 4, g = G & 15;
    int sw = g ^ (r & 15);
    *(float4*)&As[(r*16 + sw)*8] = *(const float4*)&Arow[(size_t)G*8];
    *(float4*)&Bs[(r*16 + sw)*8] = *(const float4*)&Brow[(size_t)G*8];
  }
  __syncthreads();
  int w = t >> 6, lane = t & 63;
  int rw = (w >> 1)*64, cw = (w & 1)*64;
  int m15 = lane & 15, quad = lane >> 4;
  float4_ acc[4][4] = {};
  #pragma unroll
  for (int kq = 0; kq < 4; kq++) {
    short8 a[4], b[4];
    int g = kq*4 + quad;
    #pragma unroll
    for (int mi = 0; mi < 4; mi++) {
      int r = rw + mi*16 + m15;
      a[mi] = *(const short8*)&As[(r*16 + (g ^ (r & 15)))*8];
    }
    #pragma unroll
    for (int ni = 0; ni < 4; ni++) {
      int r = cw + ni*16 + m15;
      b[ni] = *(const short8*)&Bs[(r*16 + (g ^ (r & 15)))*8];
    }
    #pragma unroll
    for (int mi = 0; mi < 4; mi++)
      #pragma unroll
      for (int ni = 0; ni < 4; ni++)
        acc[mi][ni] = __builtin_amdgcn_mfma_f32_16x16x32_bf16(a[mi], b[ni], acc[mi][ni], 0, 0, 0);
  }
  int i0 = blockIdx.x*128, j0 = blockIdx.y*128;
  float* diag = dg_all + z*NS;
  float* rrow = rsp + ((size_t)z*64 + blockIdx.y*2 + (w & 1))*NS;
  float* crow = csp + ((size_t)z*64 + blockIdx.x*2 + (w >> 1))*NS;
  float cs[4] = {0,0,0,0};
  #pragma unroll
  for (int mi = 0; mi < 4; mi++) {
    float rs[4] = {0,0,0,0};
    #pragma unroll
    for (int ni = 0; ni < 4; ni++) {
      #pragma unroll
      for (int reg = 0; reg < 4; reg++) {
        float sim2 = acc[mi][ni][reg]*2.0f;
        int gi = i0 + rw + mi*16 + quad*4 + reg;     // C/D: row=(lane>>4)*4+reg
        int gj = j0 + cw + ni*16 + m15;              //      col=lane&15
        if (gi == gj) diag[gi] = sim2;
        float e = __expf(sim2);
        rs[reg] += e; cs[ni] += e;
      }
    }
    #pragma unroll
    for (int reg = 0; reg < 4; reg++) {
      float v = rs[reg];
      v += __shfl_xor(v, 1); v += __shfl_xor(v, 2);
      v += __shfl_xor(v, 4); v += __shfl_xor(v, 8);
      if (m15 == 0) rrow[i0 + rw + mi*16 + quad*4 + reg] = v;
    }
  }
  #pragma unroll
  for (int ni = 0; ni < 4; ni++) {
    float v = cs[ni];
    v += __shfl_xor(v, 16); v += __shfl_xor(v, 32);
    if (quad == 0) crow[j0 + cw + ni*16 + m15] = v;
  }
}

// reduce partials -> per-block loss partial (grid (16,2))
__global__ void k_lred(const float* __restrict__ rsp, const float* __restrict__ csp,
                       const float* __restrict__ dg_all, float* __restrict__ pbuf) {
  __shared__ float red[256];
  int z = blockIdx.y;
  int i = blockIdx.x*256 + threadIdx.x;
  float rs = 0.f, cs = 0.f;
  for (int s = 0; s < 64; s++) {
    rs += rsp[((size_t)z*64 + s)*NS + i];
    cs += csp[((size_t)z*64 + s)*NS + i];
  }
  float v = logf(rs) + logf(cs) - 2.f*dg_all[z*NS + i];
  red[threadIdx.x] = v; __syncthreads();
  for (int off = 128; off; off >>= 1) {
    if (threadIdx.x < off) red[threadIdx.x] += red[threadIdx.x + off];
    __syncthreads();
  }
  if (threadIdx.x == 0) pbuf[z*16 + blockIdx.x] = red[0];
}

extern "C" void kernel_launch(void* const* d_in, const int* in_sizes, int n_in,
                              void* d_out, int out_size, void* d_ws, size_t ws_size,
                              hipStream_t stream) {
  const float* E_stu  = (const float*)d_in[0];
  const float* E_exer = (const float*)d_in[1];
  const float* E_k    = (const float*)d_in[2];
  const float* W1  = (const float*)d_in[3];
  const float* a1s = (const float*)d_in[4];
  const float* a1d = (const float*)d_in[5];
  const float* W2  = (const float*)d_in[6];
  const float* a2s = (const float*)d_in[7];
  const float* a2d = (const float*)d_in[8];
  const float* pW1 = (const float*)d_in[9];
  const float* pW2 = (const float*)d_in[10];
  const float* pW3 = (const float*)d_in[11];
  const float* pb3 = (const float*)d_in[12];
  const float* kn_r = (const float*)d_in[13];
  const int* stu_ids  = (const int*)d_in[14];
  const int* exer_ids = (const int*)d_in[15];
  const int* k_ids    = (const int*)d_in[16];
  EdgePtrs ep;
  for (int g = 0; g < 3; g++) {
    ep.s_src[g] = (const int*)d_in[17 + g*4];
    ep.s_dst[g] = (const int*)d_in[18 + g*4];
    ep.e_src[g] = (const int*)d_in[19 + g*4];
    ep.e_dst[g] = (const int*)d_in[20 + g*4];
  }
  const int* stu_index  = (const int*)d_in[29];
  const int* exer_index = (const int*)d_in[30];
  float* out = (float*)d_out;   // [0..8191] predictions, [8192] closs

  // ---- workspace carve ----
  char* p = (char*)d_ws;
  auto carve = [&](size_t bytes) -> char* {
    char* r = p; p += (bytes + 255) & ~(size_t)255; return r;
  };
  const size_t NODE_F = (size_t)NNODE*KD;
  float* ssb = (float*)carve((size_t)8*NNODE*4);
  float* ss0 = ssb,            *sd0 = ssb + NNODE;
  float* ss3 = ssb + 2*NNODE,  *sd3 = ssb + 5*NNODE;
  unsigned short* hb0 = (unsigned short*)carve(NODE_F*2);        // layer-1 h (shared)
  unsigned short* hb3 = (unsigned short*)carve(3*NODE_F*2);      // layer-2 h x3
  // time-multiplexed: CSR partials (6.4 MB) -> layer-1 agg bf16 out (6.4 MB)
  char* Creg = carve((size_t)8*HB*NNODE*4);
  int*   part = (int*)Creg;                       // part[3][HB][NNODE]
  int*   boff = (int*)Creg + (size_t)3*HB*NNODE;  // boff[3][HB][NNODE]
  unsigned short* etb = (unsigned short*)Creg;    // layer-1 agg out, bf16 [3*NNODE][KD]
  float* eoutAll = (float*)carve((size_t)(NS + NE)*KD*4);        // main-graph layer-2 out
  int* cnt_all = (int*)carve((size_t)3*NNODE*4);
  int* rp_all  = (int*)carve((size_t)3*RP*4);
  unsigned short* col_all = (unsigned short*)carve((size_t)3*NCSR*2);
  float* pWT = (float*)carve((size_t)3*KD*KD*4);
  float* pW1T = pWT, *pW2T = pWT + KD*KD, *pW3T = pWT + 2*KD*KD;
  float* rsp = (float*)carve((size_t)2*64*NS*4);   // rowsum partials
  float* csp = (float*)carve((size_t)2*64*NS*4);   // colsum partials
  float* dg_all = (float*)carve((size_t)2*NS*4);
  float* pbuf = (float*)carve(64*4);
  unsigned short* Z = (unsigned short*)carve((size_t)2*8192*KD*2);  // bf16 Z1|Z2

  // ---- fused: CSR hist ∪ layer-1 GEMM ∪ weight transpose (independent) ----
  k_fuse1<<<3*HB + NNODE/32 + 48, 256, 0, stream>>>(
      ep, part, W1, a1s, a1d, hb0, ss0, sd0,
      E_stu, E_exer, E_k, stu_ids, exer_ids, k_ids,
      pW1, pW2, pW3, pWT);

  // ---- CSR scan chain ----
  k_sumpart<<<(3*NNODE + 255)/256, 256, 0, stream>>>(part, cnt_all);
  k_scan<<<3, 1024, 0, stream>>>(cnt_all, rp_all);
  k_boff<<<(3*NNODE + 255)/256, 256, 0, stream>>>(part, rp_all, boff);
  k_scatter<<<dim3(HB, 3), 256, 0, stream>>>(ep, boff, col_all);

  // ---- GAT layer 1 aggregation (batched) ----
  k_agg<<<3*NNODE/4, 256, 0, stream>>>(rp_all, col_all, hb0, ss0, sd0, etb,
                                       nullptr, nullptr, -1);

  // ---- GAT layer 2 (bf16 input; batched agg) ----
  k_ngemm<0><<<3*NNODE/32, 256, 0, stream>>>(etb, W2, nullptr, nullptr, a2s, a2d,
                                             nullptr, hb3, ss3, sd3, 3*NNODE,
                                             nullptr, nullptr, nullptr);
  k_agg<<<3*NNODE/4, 256, 0, stream>>>(rp_all, col_all, hb3, ss3, sd3, nullptr,
                                       eoutAll, Z, -2);

  // ---- contrastive loss (bf16 MFMA sim, atomic-free epilogue) ----
  k_sim<<<dim3(32, 32, 2), 256, 0, stream>>>(Z, rsp, csp, dg_all);
  k_lred<<<dim3(16, 2), 256, 0, stream>>>(rsp, csp, dg_all, pbuf);

  // ---- prediction head (fused; block 0 also finalizes closs from pbuf) ----
  k_ngemm<4><<<BQ/16, 256, 0, stream>>>(nullptr, pW1T, pW2T, pW3T, pb3, kn_r,
                                        out, nullptr, nullptr, pbuf, BQ,
                                        eoutAll, stu_index, exer_index);
}